// Round 9
// baseline (5757.208 us; speedup 1.0000x reference)
//
#include <hip/hip_runtime.h>
#include <hip/hip_bf16.h>

#define BB 64
#define TT_ 512
#define IN_ 256
#define HH 1024
#define G4 4096
#define OO 256

typedef _Float16 half8 __attribute__((ext_vector_type(8)));
typedef float f32x4 __attribute__((ext_vector_type(4)));
typedef unsigned int uint4v __attribute__((ext_vector_type(4)));
typedef int int4v __attribute__((ext_vector_type(4)));

__device__ __forceinline__ float sigmoidf_(float v) {
    return 1.f / (1.f + __expf(-v));
}
__device__ __forceinline__ float tanhf_(float v) {
    float vc = fminf(fmaxf(v, -15.f), 15.f);
    float e = __expf(2.f * vc);
    return (e - 1.f) / (e + 1.f);
}

// ---------------- encoder weight pack ----------------
// Apk[jt(256)][kc(40)][lane(64)][e(8)] fp16; jt = global 4-dim tile (= d>>2).
// Tile rows rD = ddl*4 + g -> MFMA acc[r] of lane (ddl=l>>4) holds gate r of
// dim jt*4 + ddl. kc 0..31 = Whh K, kc 32..39 = Wih K.
__global__ __launch_bounds__(256)
void pack_a2(const float* __restrict__ Whh, const float* __restrict__ Wih,
             _Float16* __restrict__ Apk)
{
    int id = blockIdx.x * 256 + threadIdx.x;      // 16B-unit id < 655360
    int dq  = id / 5120;
    int r1  = id - dq * 5120;
    int t2  = r1 / 2560;
    int r2  = r1 - t2 * 2560;
    int kc  = r2 >> 6, l = r2 & 63;
    int rD  = l & 15;
    int g   = rD & 3, ddl = rD >> 2;
    int d   = dq * 8 + t2 * 4 + ddl;
    int j   = g * HH + d;
    int k0  = kc * 32 + ((l >> 4) << 3);
    half8 v;
    if (kc < 32) {
        const float* s = Whh + (size_t)j * HH + k0;
#pragma unroll
        for (int e = 0; e < 8; ++e) v[e] = (_Float16)s[e];
    } else {
        const float* s = Wih + (size_t)j * IN_ + (k0 - 1024);
#pragma unroll
        for (int e = 0; e < 8; ++e) v[e] = (_Float16)s[e];
    }
    ((half8*)Apk)[id] = v;
}

// ---------------- decoder weight pack ----------------
__global__ __launch_bounds__(256)
void pack_adec(const float* __restrict__ Wih, _Float16* __restrict__ Adecpk)
{
    int id = blockIdx.x * 256 + threadIdx.x;      // < 131072
    int dq = id >> 10;
    int r1 = id & 1023;
    int t2 = r1 >> 9;
    int r2 = r1 & 511;
    int kc2 = r2 >> 6, l = r2 & 63;
    int rD = l & 15, g = rD & 3, ddl = rD >> 2;
    int d  = dq * 8 + t2 * 4 + ddl;
    int j  = g * HH + d;
    int k0 = kc2 * 32 + ((l >> 4) << 3);
    const float* s = Wih + (size_t)j * IN_ + k0;
    half8 v;
#pragma unroll
    for (int e = 0; e < 8; ++e) v[e] = (_Float16)s[e];
    ((half8*)Adecpk)[id] = v;
}

// ---------------- FC weight pack ----------------
__global__ __launch_bounds__(256)
void pack_fcw(const float* __restrict__ fcW, _Float16* __restrict__ fcWpk)
{
    int id = blockIdx.x * 256 + threadIdx.x;      // < 32768
    int ot = id >> 11;
    int r  = id & 2047;
    int kc = r >> 6, l = r & 63;
    int o  = ot * 16 + (l & 15);
    int k0 = kc * 32 + ((l >> 4) << 3);
    const float* s = fcW + (size_t)o * HH + k0;
    half8 v;
#pragma unroll
    for (int e = 0; e < 8; ++e) v[e] = (_Float16)s[e];
    ((half8*)fcWpk)[id] = v;
}

// ---------------- x pack ----------------
__global__ __launch_bounds__(256)
void pack_x(const float* __restrict__ x, _Float16* __restrict__ Xpk)
{
    int id = blockIdx.x * 256 + threadIdx.x;  // < 1048576
    int l = id & 63, bt = (id >> 6) & 3, kc2 = (id >> 8) & 7, t = id >> 11;
    int b  = bt * 16 + (l & 15);
    int i0 = kc2 * 32 + ((l >> 4) << 3);
    const float* s = x + ((size_t)b * TT_ + t) * IN_ + i0;
    half8 v;
#pragma unroll
    for (int e = 0; e < 8; ++e) v[e] = (_Float16)s[e];
    ((half8*)Xpk)[id] = v;
}

__global__ __launch_bounds__(256)
void pack_bias(const float* __restrict__ bih, const float* __restrict__ bhh,
               float* __restrict__ biasc)
{
    int j = blockIdx.x * 256 + threadIdx.x;
    if (j < G4) biasc[j] = bih[j] + bhh[j];
}

// ---------------- persistent encoder v5 ----------------
// grid 256 = (dq16 = bid>>2, grp = bid&3), block 512 (8 waves).
// Wave w = (tile = w&3, kh = w>>2): 4 dims x 4 gates x 16 batches, K-half.
// A-frags (20/wave = 80 VGPR) in registers. H (32KB group slice) staged to LDS
// per step by all 8 waves. K-half partials exchanged via 4KB LDS (kh1 writes,
// kh0 = gate threads add their own in-register half). Arrival = atomicAdd to
// 16 spaced counters per group; 4-deep software-pipelined sc0sc1 poll.
// 2 syncthreads per step; no HW fences.
__global__ __launch_bounds__(512, 2)
void enc_persist(const _Float16* __restrict__ Apk,
                 const _Float16* __restrict__ Xpk,
                 _Float16* __restrict__ Hbuf0,
                 _Float16* __restrict__ Hbuf1,
                 const float* __restrict__ biasc,
                 float* __restrict__ cT,
                 float* __restrict__ hT,
                 int* __restrict__ ctr)
{
    __shared__ __align__(16) _Float16 Hst[32 * 64 * 8];   // 32 KB
    __shared__ __align__(16) f32x4 pp[4 * 64];            // 4 KB (kh1 partials)
    const int tid  = threadIdx.x;
    const int lane = tid & 63, w = tid >> 6;
    const int tile = w & 3, kh = w >> 2;
    const int dq16 = blockIdx.x >> 2, grp = blockIdx.x & 3;
    const int ddl = lane >> 4, bl = lane & 15;
    const int d = dq16 * 16 + tile * 4 + ddl;
    const int b = grp * 16 + bl;
    const int jt = dq16 * 4 + tile;

    // ---- one-time: A-frags -> registers (20/wave, static unroll) ----
    half8 areg[20];
    {
        const half8* src = (const half8*)Apk + ((size_t)jt * 40 + kh * 20) * 64 + lane;
#pragma unroll
        for (int i = 0; i < 20; ++i) areg[i] = src[i * 64];
    }
    f32x4 bsum;
#pragma unroll
    for (int g = 0; g < 4; ++g) bsum[g] = biasc[g * HH + d];

    const half8* Hld8 = (const half8*)Hst;
    uint4v* Hst16 = (uint4v*)Hst;
    int* mycnt = ctr + ((grp * 16 + (dq16 >> 2)) << 4);
    const int* cp = ctr + ((grp * 16 + (lane & 15)) << 4);

    float c_reg = 0.f, h_last = 0.f;

    for (int t = 0; t < TT_; ++t) {
        const _Float16* Hin = (t & 1) ? Hbuf1 : Hbuf0;
        _Float16* Hout      = (t & 1) ? Hbuf0 : Hbuf1;

        // ---- stage H: 4 x dwordx4/thread (sc0sc1, pipelined) ----
        const uint4v* Hsrc = (const uint4v*)Hin + (size_t)grp * 2048;
        uint4v tmp[4];
#pragma unroll
        for (int i = 0; i < 4; ++i) {
            asm volatile("global_load_dwordx4 %0, %1, off sc0 sc1"
                         : "=v"(tmp[i]) : "v"(Hsrc + i * 512 + tid));
        }
        // X B-frags for kh1 waves (plain cached loads, hide under H trip)
        half8 xf[8];
        if (kh) {
            const half8* X8 = (const half8*)Xpk + ((size_t)t * 32 + grp) * 64 + lane;
#pragma unroll
            for (int k = 0; k < 8; ++k) xf[k] = X8[k * 256];
        }
        asm volatile("s_waitcnt vmcnt(0)" ::: "memory");
#pragma unroll
        for (int i = 0; i < 4; ++i) Hst16[i * 512 + tid] = tmp[i];
        __syncthreads();   // stage-sync

        // ---- MFMA: this wave's K-half (A regs x B LDS/regs), 2 chains ----
        f32x4 acc0 = {0.f, 0.f, 0.f, 0.f};
        f32x4 acc1 = {0.f, 0.f, 0.f, 0.f};
        if (kh == 0) {
#pragma unroll
            for (int i = 0; i < 20; ++i) {
                half8 bf = Hld8[i * 64 + lane];
                if (i & 1)
                    acc1 = __builtin_amdgcn_mfma_f32_16x16x32_f16(areg[i], bf, acc1, 0, 0, 0);
                else
                    acc0 = __builtin_amdgcn_mfma_f32_16x16x32_f16(areg[i], bf, acc0, 0, 0, 0);
            }
        } else {
#pragma unroll
            for (int i = 0; i < 12; ++i) {
                half8 bf = Hld8[(20 + i) * 64 + lane];
                if (i & 1)
                    acc1 = __builtin_amdgcn_mfma_f32_16x16x32_f16(areg[i], bf, acc1, 0, 0, 0);
                else
                    acc0 = __builtin_amdgcn_mfma_f32_16x16x32_f16(areg[i], bf, acc0, 0, 0, 0);
            }
#pragma unroll
            for (int k = 0; k < 8; ++k) {
                if (k & 1)
                    acc1 = __builtin_amdgcn_mfma_f32_16x16x32_f16(areg[12 + k], xf[k], acc1, 0, 0, 0);
                else
                    acc0 = __builtin_amdgcn_mfma_f32_16x16x32_f16(areg[12 + k], xf[k], acc0, 0, 0, 0);
            }
        }
        f32x4 acc = acc0 + acc1;

        // ---- K-half exchange: kh1 writes partials; gate threads (kh0) add ----
        if (kh == 1) pp[tile * 64 + lane] = acc;
        __syncthreads();   // exchange-sync

        if (kh == 0) {
            f32x4 o = pp[tile * 64 + lane];
            float pi = acc[0] + o[0] + bsum[0];
            float pf = acc[1] + o[1] + bsum[1];
            float pg = acc[2] + o[2] + bsum[2];
            float po = acc[3] + o[3] + bsum[3];
            float ig = sigmoidf_(pi), fg = sigmoidf_(pf);
            float gg = tanhf_(pg),    og = sigmoidf_(po);
            c_reg = fg * c_reg + ig * gg;
            float h = og * tanhf_(c_reg);
            h_last = h;

            // publish h in B-frag layout (pair dims via shfl, 4B sc0sc1 stores)
            float hp = __shfl_xor(h, 16);    // partner ddl^1
            if (!(ddl & 1)) {
                _Float16 h0 = (_Float16)h, h1 = (_Float16)hp;
                unsigned int pk = (unsigned int)__builtin_bit_cast(unsigned short, h0) |
                                  ((unsigned int)__builtin_bit_cast(unsigned short, h1) << 16);
                unsigned int idx = ((unsigned)grp * 2048 + ((unsigned)d >> 5) * 64 +
                                    (((unsigned)d >> 3) & 3) * 16 + bl) * 8 + (d & 7);
                asm volatile("global_store_dword %0, %1, off sc0 sc1"
                             :: "v"((unsigned int*)&Hout[idx]), "v"(pk) : "memory");
            }
            asm volatile("s_waitcnt vmcnt(0)" ::: "memory");  // drain this wave's h
            if (lane == 0)
                __hip_atomic_fetch_add(mycnt, 1, __ATOMIC_RELAXED,
                                       __HIP_MEMORY_SCOPE_AGENT);
        }

        // ---- 4-deep pipelined poll (all waves; poll IS the rendezvous) ----
        if (t < TT_ - 1) {
            int tgt = 16 * (t + 1);
            int p0, p1, p2, p3;
            asm volatile("global_load_dword %0, %4, off sc0 sc1\n\t"
                         "s_sleep 1\n\t"
                         "global_load_dword %1, %4, off sc0 sc1\n\t"
                         "s_sleep 1\n\t"
                         "global_load_dword %2, %4, off sc0 sc1\n\t"
                         "s_sleep 1\n\t"
                         "global_load_dword %3, %4, off sc0 sc1"
                         : "=&v"(p0), "=&v"(p1), "=&v"(p2), "=v"(p3)
                         : "v"(cp) : "memory");
            for (;;) {
                asm volatile("s_waitcnt vmcnt(3)" ::: "memory");
                if (__all(p0 >= tgt)) break;
                asm volatile("global_load_dword %0, %1, off sc0 sc1"
                             : "=v"(p0) : "v"(cp) : "memory");
                __builtin_amdgcn_s_sleep(1);
                asm volatile("s_waitcnt vmcnt(3)" ::: "memory");
                if (__all(p1 >= tgt)) break;
                asm volatile("global_load_dword %0, %1, off sc0 sc1"
                             : "=v"(p1) : "v"(cp) : "memory");
                __builtin_amdgcn_s_sleep(1);
                asm volatile("s_waitcnt vmcnt(3)" ::: "memory");
                if (__all(p2 >= tgt)) break;
                asm volatile("global_load_dword %0, %1, off sc0 sc1"
                             : "=v"(p2) : "v"(cp) : "memory");
                __builtin_amdgcn_s_sleep(1);
                asm volatile("s_waitcnt vmcnt(3)" ::: "memory");
                if (__all(p3 >= tgt)) break;
                asm volatile("global_load_dword %0, %1, off sc0 sc1"
                             : "=v"(p3) : "v"(cp) : "memory");
                __builtin_amdgcn_s_sleep(1);
            }
            // keep p0..p3 live until all outstanding poll loads retire
            asm volatile("s_waitcnt vmcnt(0)"
                         : "+v"(p0), "+v"(p1), "+v"(p2), "+v"(p3) :: "memory");
        }
    }

    // ---- final state for decoder ----
    if (kh == 0) {
        cT[d * 64 + b] = c_reg;
        hT[d * 64 + b] = h_last;
    }
}

// ---------------- hdecg = h_final @ dec_Whh^T + biases (gate-major out) ----------------
__global__ __launch_bounds__(256)
void hdec_kernel(const float* __restrict__ hT, const float* __restrict__ Whh,
                 const float* __restrict__ bih, const float* __restrict__ bhh,
                 float* __restrict__ hdecg)
{
    __shared__ float hb[1024];
    const int tid = threadIdx.x;
    const int b  = blockIdx.x >> 2;
    const int j0 = (blockIdx.x & 3) * 1024;
#pragma unroll
    for (int u = 0; u < 4; ++u) {
        int k = u * 256 + tid;
        hb[k] = hT[k * 64 + b];
    }
    __syncthreads();
#pragma unroll
    for (int rr = 0; rr < 4; ++rr) {
        int j = j0 + rr * 256 + tid;
        const float* wr = Whh + (size_t)j * HH;
        float a = bih[j] + bhh[j];
        for (int k = 0; k < 1024; k += 4) {
            float4 wv = *(const float4*)(wr + k);
            float4 hv = *(const float4*)&hb[k];
            a += hv.x * wv.x + hv.y * wv.y + hv.z * wv.z + hv.w * wv.w;
        }
        hdecg[((size_t)(j >> 10) * 1024 + (j & 1023)) * 64 + b] = a;
    }
}

// ---------------- MFMA decoder (unchanged) ----------------
__global__ __launch_bounds__(256)
void dec_mfma(const _Float16* __restrict__ Adecpk,
              const _Float16* __restrict__ fcWpk,
              const _Float16* __restrict__ Xpk,
              const float* __restrict__ hdecg,
              const float* __restrict__ cT,
              const float* __restrict__ fcb,
              float* __restrict__ out)
{
    __shared__ __align__(16) _Float16 Hn[32 * 64 * 8];   // 32 KB
    __shared__ __align__(16) float outl[16][260];
    const int tid = threadIdx.x;
    const int lane = tid & 63, w = tid >> 6;
    const int t = blockIdx.x >> 2, bq4 = blockIdx.x & 3;
    const int q = lane >> 4, bl = lane & 15;
    const int bg = bq4 * 16 + bl;

    const half8* X8 = (const half8*)Xpk + ((size_t)t * 32 + bq4) * 64 + lane;
    half8 xf[8];
#pragma unroll
    for (int kc2 = 0; kc2 < 8; ++kc2) xf[kc2] = X8[kc2 * 256];

    const half8* AD = (const half8*)Adecpk + lane;
    for (int dqi = 0; dqi < 32; ++dqi) {
        int dq = w * 32 + dqi;
#pragma unroll
        for (int t2 = 0; t2 < 2; ++t2) {
            f32x4 acc = {0.f, 0.f, 0.f, 0.f};
#pragma unroll
            for (int kc2 = 0; kc2 < 8; ++kc2) {
                half8 a = AD[((size_t)(dq * 2 + t2) * 8 + kc2) * 64];
                acc = __builtin_amdgcn_mfma_f32_16x16x32_f16(a, xf[kc2], acc, 0, 0, 0);
            }
            int d = dq * 8 + t2 * 4 + q;
            float cv = cT[d * 64 + bg];
            float pi = acc[0] + hdecg[(size_t)(0 * HH + d) * 64 + bg];
            float pf = acc[1] + hdecg[(size_t)(1 * HH + d) * 64 + bg];
            float pg = acc[2] + hdecg[(size_t)(2 * HH + d) * 64 + bg];
            float po = acc[3] + hdecg[(size_t)(3 * HH + d) * 64 + bg];
            float ig = sigmoidf_(pi), fg = sigmoidf_(pf);
            float gg = tanhf_(pg),    og = sigmoidf_(po);
            float cn = fg * cv + ig * gg;
            float h = og * tanhf_(cn);
            Hn[((d >> 5) * 64 + ((d >> 3) & 3) * 16 + bl) * 8 + (d & 7)] = (_Float16)h;
        }
    }
    __syncthreads();

    const half8* Hn8 = (const half8*)Hn + lane;
    const half8* FW = (const half8*)fcWpk + lane;
#pragma unroll
    for (int oti = 0; oti < 4; ++oti) {
        int ot = w * 4 + oti;
        f32x4 acc = {0.f, 0.f, 0.f, 0.f};
        for (int kc = 0; kc < 32; ++kc) {
            half8 a  = FW[((size_t)ot * 32 + kc) * 64];
            half8 bf = Hn8[kc * 64];
            acc = __builtin_amdgcn_mfma_f32_16x16x32_f16(a, bf, acc, 0, 0, 0);
        }
#pragma unroll
        for (int r = 0; r < 4; ++r) {
            int o = ot * 16 + q * 4 + r;
            outl[bl][o] = acc[r] + fcb[o];
        }
    }
    __syncthreads();

#pragma unroll
    for (int i = 0; i < 16; ++i) {
        int b = bq4 * 16 + i;
        out[((size_t)b * TT_ + t) * OO + tid] = outl[i][tid];
    }
}

extern "C" void kernel_launch(void* const* d_in, const int* in_sizes, int n_in,
                              void* d_out, int out_size, void* d_ws, size_t ws_size,
                              hipStream_t stream) {
    const float* x    = (const float*)d_in[0];
    const float* eWih = (const float*)d_in[1];
    const float* eWhh = (const float*)d_in[2];
    const float* ebih = (const float*)d_in[3];
    const float* ebhh = (const float*)d_in[4];
    const float* dWih = (const float*)d_in[5];
    const float* dWhh = (const float*)d_in[6];
    const float* dbih = (const float*)d_in[7];
    const float* dbhh = (const float*)d_in[8];
    const float* fcW  = (const float*)d_in[9];
    const float* fcb  = (const float*)d_in[10];

    // ws layout (f32 words): hT 65536 | cT 65536 | hdecg 262144 | biasc 4096 |
    // ctr 1024 | fp16: Hf0 65536 | Hf1 65536 | Apk 5242880 | Xpk 8388608 |
    // Adecpk 1048576 | fcWpk 262144
    float* ws    = (float*)d_ws;
    float* hT    = ws;
    float* cT    = ws + 65536;
    float* hdecg = ws + 131072;
    float* biasc = ws + 393216;
    int*   ctr   = (int*)(ws + 397312);
    _Float16* fp  = (_Float16*)(ws + 398336);
    _Float16* Hf0 = fp;
    _Float16* Hf1 = fp + 65536;
    _Float16* Apk = fp + 131072;
    _Float16* Xpk = Apk + 5242880;
    _Float16* Adecpk = Xpk + 8388608;
    _Float16* fcWpk  = Adecpk + 1048576;

    pack_a2<<<dim3(2560), dim3(256), 0, stream>>>(eWhh, eWih, Apk);
    pack_x<<<dim3(4096), dim3(256), 0, stream>>>(x, Xpk);
    pack_bias<<<dim3(16), dim3(256), 0, stream>>>(ebih, ebhh, biasc);
    pack_adec<<<dim3(512), dim3(256), 0, stream>>>(dWih, Adecpk);
    pack_fcw<<<dim3(128), dim3(256), 0, stream>>>(fcW, fcWpk);
    hipMemsetAsync(ctr, 0, 1024 * sizeof(int), stream);
    hipMemsetAsync(Hf0, 0, 65536 * sizeof(_Float16), stream);

    enc_persist<<<dim3(256), dim3(512), 0, stream>>>(
        Apk, Xpk, Hf0, Hf1, biasc, cT, hT, ctr);

    hdec_kernel<<<dim3(256), dim3(256), 0, stream>>>(hT, dWhh, dbih, dbhh, hdecg);
    dec_mfma<<<dim3(2048), dim3(256), 0, stream>>>(Adecpk, fcWpk, Xpk, hdecg, cT,
                                                   fcb, (float*)d_out);
}

// Round 10
// 4605.368 us; speedup vs baseline: 1.2501x; 1.2501x over previous
//
#include <hip/hip_runtime.h>
#include <hip/hip_bf16.h>

#define BB 64
#define TT_ 512
#define IN_ 256
#define HH 1024
#define G4 4096
#define OO 256

typedef _Float16 half8 __attribute__((ext_vector_type(8)));
typedef float f32x4 __attribute__((ext_vector_type(4)));
typedef unsigned int uint4v __attribute__((ext_vector_type(4)));
typedef int int4v __attribute__((ext_vector_type(4)));

__device__ __forceinline__ float sigmoidf_(float v) {
    return 1.f / (1.f + __expf(-v));
}
__device__ __forceinline__ float tanhf_(float v) {
    float vc = fminf(fmaxf(v, -15.f), 15.f);
    float e = __expf(2.f * vc);
    return (e - 1.f) / (e + 1.f);
}

// ---------------- encoder weight pack ----------------
// Apk[jt(256)][kc(40)][lane(64)][e(8)] fp16; jt = global 4-dim tile (= d>>2).
// Tile rows rD = ddl*4 + g -> MFMA acc[r] of lane (q=l>>4) holds gate r of
// dim jt*4 + q. kc 0..31 = Whh K, kc 32..39 = Wih K.
__global__ __launch_bounds__(256)
void pack_a2(const float* __restrict__ Whh, const float* __restrict__ Wih,
             _Float16* __restrict__ Apk)
{
    int id = blockIdx.x * 256 + threadIdx.x;      // 16B-unit id < 655360
    int dq  = id / 5120;
    int r1  = id - dq * 5120;
    int t2  = r1 / 2560;
    int r2  = r1 - t2 * 2560;
    int kc  = r2 >> 6, l = r2 & 63;
    int rD  = l & 15;
    int g   = rD & 3, ddl = rD >> 2;
    int d   = dq * 8 + t2 * 4 + ddl;
    int j   = g * HH + d;
    int k0  = kc * 32 + ((l >> 4) << 3);
    half8 v;
    if (kc < 32) {
        const float* s = Whh + (size_t)j * HH + k0;
#pragma unroll
        for (int e = 0; e < 8; ++e) v[e] = (_Float16)s[e];
    } else {
        const float* s = Wih + (size_t)j * IN_ + (k0 - 1024);
#pragma unroll
        for (int e = 0; e < 8; ++e) v[e] = (_Float16)s[e];
    }
    ((half8*)Apk)[id] = v;
}

// ---------------- decoder weight pack ----------------
__global__ __launch_bounds__(256)
void pack_adec(const float* __restrict__ Wih, _Float16* __restrict__ Adecpk)
{
    int id = blockIdx.x * 256 + threadIdx.x;      // < 131072
    int dq = id >> 10;
    int r1 = id & 1023;
    int t2 = r1 >> 9;
    int r2 = r1 & 511;
    int kc2 = r2 >> 6, l = r2 & 63;
    int rD = l & 15, g = rD & 3, ddl = rD >> 2;
    int d  = dq * 8 + t2 * 4 + ddl;
    int j  = g * HH + d;
    int k0 = kc2 * 32 + ((l >> 4) << 3);
    const float* s = Wih + (size_t)j * IN_ + k0;
    half8 v;
#pragma unroll
    for (int e = 0; e < 8; ++e) v[e] = (_Float16)s[e];
    ((half8*)Adecpk)[id] = v;
}

// ---------------- FC weight pack ----------------
__global__ __launch_bounds__(256)
void pack_fcw(const float* __restrict__ fcW, _Float16* __restrict__ fcWpk)
{
    int id = blockIdx.x * 256 + threadIdx.x;      // < 32768
    int ot = id >> 11;
    int r  = id & 2047;
    int kc = r >> 6, l = r & 63;
    int o  = ot * 16 + (l & 15);
    int k0 = kc * 32 + ((l >> 4) << 3);
    const float* s = fcW + (size_t)o * HH + k0;
    half8 v;
#pragma unroll
    for (int e = 0; e < 8; ++e) v[e] = (_Float16)s[e];
    ((half8*)fcWpk)[id] = v;
}

// ---------------- x pack ----------------
__global__ __launch_bounds__(256)
void pack_x(const float* __restrict__ x, _Float16* __restrict__ Xpk)
{
    int id = blockIdx.x * 256 + threadIdx.x;  // < 1048576
    int l = id & 63, bt = (id >> 6) & 3, kc2 = (id >> 8) & 7, t = id >> 11;
    int b  = bt * 16 + (l & 15);
    int i0 = kc2 * 32 + ((l >> 4) << 3);
    const float* s = x + ((size_t)b * TT_ + t) * IN_ + i0;
    half8 v;
#pragma unroll
    for (int e = 0; e < 8; ++e) v[e] = (_Float16)s[e];
    ((half8*)Xpk)[id] = v;
}

__global__ __launch_bounds__(256)
void pack_bias(const float* __restrict__ bih, const float* __restrict__ bhh,
               float* __restrict__ biasc)
{
    int j = blockIdx.x * 256 + threadIdx.x;
    if (j < G4) biasc[j] = bih[j] + bhh[j];
}

// ---------------- persistent encoder v6 (R8 base + serial-chain fixes) ----------------
// grid 256 = (dq16 = bid>>2, grp = bid&3), block 256 (4 waves, 1 WG/CU).
// Wave t4 = one 16-row tile (4 dims x 4 gates) x 16 batches, full K.
// Whh A-frags in LDS (128 KB, once). Per step: acquire-agent fence (wave0) ->
// plain cached H loads (L2 shares the broadcast within an XCD) -> X-MFMAs from
// prefetched regs under H shadow -> stage H to LDS -> 32 H-MFMAs -> gates in-reg
// -> publish h (sc0sc1 4B) -> per-wave flag -> 2-deep pipelined dwordx4 poll.
__global__ __launch_bounds__(256, 1)
void enc_persist(const _Float16* __restrict__ Apk,
                 const _Float16* __restrict__ Xpk,
                 _Float16* __restrict__ Hbuf0,
                 _Float16* __restrict__ Hbuf1,
                 const float* __restrict__ biasc,
                 float* __restrict__ cT,
                 float* __restrict__ hT,
                 int* __restrict__ flags)
{
    __shared__ __align__(16) _Float16 Ald[4 * 32 * 64 * 8];   // 128 KB
    __shared__ __align__(16) _Float16 Hst[32 * 64 * 8];       // 32 KB
    const int tid  = threadIdx.x;
    const int lane = tid & 63, t4 = tid >> 6;
    const int dq16 = blockIdx.x >> 2, grp = blockIdx.x & 3;
    const int q = lane >> 4, bl = lane & 15;
    const int d = dq16 * 16 + t4 * 4 + q;        // this thread's dim
    const int b = grp * 16 + bl;                 // this thread's batch
    const int jt = dq16 * 4 + t4;                // this wave's A-tile

    // ---- one-time: Whh A-frags -> LDS ----
    {
        const half8* src = (const half8*)Apk + ((size_t)jt * 40) * 64 + lane;
        half8* dst = (half8*)Ald + (size_t)t4 * 32 * 64 + lane;
#pragma unroll
        for (int kc = 0; kc < 32; ++kc) dst[kc * 64] = src[kc * 64];
    }
    // ---- one-time: Wih A-frags -> registers (8 frags, proven safe in R8) ----
    half8 xa[8];
    {
        const half8* src = (const half8*)Apk + ((size_t)jt * 40 + 32) * 64 + lane;
#pragma unroll
        for (int k = 0; k < 8; ++k) xa[k] = src[k * 64];
    }

    float bsum[4];
#pragma unroll
    for (int g = 0; g < 4; ++g) bsum[g] = biasc[g * HH + d];

    const half8* Ald8 = (const half8*)Ald + (size_t)t4 * 32 * 64 + lane;
    const half8* Hld8 = (const half8*)Hst + lane;
    uint4v* Hst16 = (uint4v*)Hst;

    // ---- prologue: xf(0) prefetch (plain cached, 8 x dwordx4) ----
    uint4v xcur[8], xnext[8];
    {
        const uint4v* X16 = (const uint4v*)Xpk + (size_t)grp * 64 + lane;   // t=0
#pragma unroll
        for (int k = 0; k < 8; ++k) {
            asm volatile("global_load_dwordx4 %0, %1, off"
                         : "=v"(xcur[k]) : "v"(X16 + k * 256));
        }
    }

    float c_reg = 0.f, h_last = 0.f;
    __syncthreads();   // A-LDS ready

    for (int t = 0; t < TT_; ++t) {
        const _Float16* Hin = (t & 1) ? Hbuf1 : Hbuf0;
        _Float16* Hout      = (t & 1) ? Hbuf0 : Hbuf1;

        // ---- issue H loads (plain cached; fence at end of prev iter) ----
        const uint4v* Hsrc = (const uint4v*)Hin + (size_t)grp * 2048;
        uint4v tmp[8];
#pragma unroll
        for (int i = 0; i < 8; ++i) {
            asm volatile("global_load_dwordx4 %0, %1, off"
                         : "=v"(tmp[i]) : "v"(Hsrc + i * 256 + tid));
        }
        // wait the 8 OLDEST (xf prologue at t=0; no-op later), keep H in flight
        asm volatile("s_waitcnt vmcnt(8)" ::: "memory");
        __builtin_amdgcn_sched_barrier(0);

        // ---- X-MFMAs under the H shadow (xcur in regs) ----
        f32x4 acc[4];
#pragma unroll
        for (int i = 0; i < 4; ++i) acc[i] = (f32x4){0.f, 0.f, 0.f, 0.f};
#pragma unroll
        for (int k = 0; k < 8; ++k) {
            half8 bf = __builtin_bit_cast(half8, xcur[k]);
            acc[k & 3] = __builtin_amdgcn_mfma_f32_16x16x32_f16(xa[k], bf, acc[k & 3], 0, 0, 0);
        }

        // ---- H arrived -> stage to LDS ----
        asm volatile("s_waitcnt vmcnt(0)" ::: "memory");
        __builtin_amdgcn_sched_barrier(0);
#pragma unroll
        for (int i = 0; i < 8; ++i) Hst16[i * 256 + tid] = tmp[i];

        // ---- prefetch xf(t+1) (plain; retires at the publish drain) ----
        {
            int tn = (t + 1 < TT_) ? t + 1 : t;
            const uint4v* Xn = (const uint4v*)Xpk + ((size_t)tn * 32 + grp) * 64 + lane;
#pragma unroll
            for (int k = 0; k < 8; ++k) {
                asm volatile("global_load_dwordx4 %0, %1, off"
                             : "=v"(xnext[k]) : "v"(Xn + k * 256));
            }
        }
        __syncthreads();   // H-LDS ready

        // ---- 32 H-MFMAs (A from LDS, B from LDS) ----
#pragma unroll
        for (int kc = 0; kc < 32; ++kc) {
            half8 a  = Ald8[kc * 64];
            half8 bf = Hld8[kc * 64];
            acc[kc & 3] = __builtin_amdgcn_mfma_f32_16x16x32_f16(a, bf, acc[kc & 3], 0, 0, 0);
        }

        // ---- gates fully in-register ----
        float pi = acc[0][0] + acc[1][0] + acc[2][0] + acc[3][0] + bsum[0];
        float pf = acc[0][1] + acc[1][1] + acc[2][1] + acc[3][1] + bsum[1];
        float pg = acc[0][2] + acc[1][2] + acc[2][2] + acc[3][2] + bsum[2];
        float po = acc[0][3] + acc[1][3] + acc[2][3] + acc[3][3] + bsum[3];
        float ig = sigmoidf_(pi), fg = sigmoidf_(pf);
        float gg = tanhf_(pg),    og = sigmoidf_(po);
        c_reg = fg * c_reg + ig * gg;
        float h = og * tanhf_(c_reg);
        h_last = h;

        // ---- publish h (B-frag layout, pair dims via shfl, 4B sc0sc1) ----
        float hp = __shfl_xor(h, 16);    // partner q^1 -> dim d^1
        if (!(q & 1)) {
            _Float16 h0 = (_Float16)h, h1 = (_Float16)hp;
            unsigned int pk = (unsigned int)__builtin_bit_cast(unsigned short, h0) |
                              ((unsigned int)__builtin_bit_cast(unsigned short, h1) << 16);
            unsigned int idx = ((unsigned)grp * 2048 + ((unsigned)d >> 5) * 64 +
                                (((unsigned)d >> 3) & 3) * 16 + bl) * 8 + (d & 7);
            asm volatile("global_store_dword %0, %1, off sc0 sc1"
                         :: "v"((unsigned int*)&Hout[idx]), "v"(pk) : "memory");
        }
        // drain this wave's h stores (+ retires xnext prefetch)
        asm volatile("s_waitcnt vmcnt(0)" ::: "memory");
        __builtin_amdgcn_sched_barrier(0);

        // rotate xf regs
#pragma unroll
        for (int k = 0; k < 8; ++k) xcur[k] = xnext[k];

        if (t < TT_ - 1) {
            // ---- per-wave arrival flag (no pre-barrier) ----
            if (lane == 0) {
                int val = t + 1;
                asm volatile("global_store_dword %0, %1, off sc0 sc1"
                             :: "v"(flags + grp * 256 + dq16 * 4 + t4), "v"(val)
                             : "memory");
            }
            // ---- wave0: 2-deep pipelined poll over the group's 256 flags ----
            if (t4 == 0) {
                const int* fp4 = flags + grp * 256 + lane * 4;
                int tgt = t + 1;
                int4v f0, f1;
                asm volatile("global_load_dwordx4 %0, %2, off sc0 sc1\n\t"
                             "s_sleep 1\n\t"
                             "global_load_dwordx4 %1, %2, off sc0 sc1"
                             : "=&v"(f0), "=v"(f1) : "v"(fp4) : "memory");
                for (;;) {
                    asm volatile("s_waitcnt vmcnt(1)" ::: "memory");
                    __builtin_amdgcn_sched_barrier(0);
                    if (__all(min(min(f0.x, f0.y), min(f0.z, f0.w)) >= tgt)) break;
                    asm volatile("global_load_dwordx4 %0, %1, off sc0 sc1"
                                 : "=v"(f0) : "v"(fp4) : "memory");
                    __builtin_amdgcn_s_sleep(1);
                    asm volatile("s_waitcnt vmcnt(1)" ::: "memory");
                    __builtin_amdgcn_sched_barrier(0);
                    if (__all(min(min(f1.x, f1.y), min(f1.z, f1.w)) >= tgt)) break;
                    asm volatile("global_load_dwordx4 %0, %1, off sc0 sc1"
                                 : "=v"(f1) : "v"(fp4) : "memory");
                    __builtin_amdgcn_s_sleep(1);
                }
                // retire stragglers while keeping f0/f1 registers alive
                asm volatile("s_waitcnt vmcnt(0)" :: "v"(f0), "v"(f1) : "memory");
                // invalidate L1/L2 so next step's plain H loads see fresh h
                __builtin_amdgcn_fence(__ATOMIC_ACQUIRE, "agent");
            }
            __syncthreads();   // release; caches clean; Hst free to overwrite
        }
    }

    // ---- final state for decoder ----
    cT[d * 64 + b] = c_reg;
    hT[d * 64 + b] = h_last;
}

// ---------------- hdecg = h_final @ dec_Whh^T + biases (gate-major out) ----------------
__global__ __launch_bounds__(256)
void hdec_kernel(const float* __restrict__ hT, const float* __restrict__ Whh,
                 const float* __restrict__ bih, const float* __restrict__ bhh,
                 float* __restrict__ hdecg)
{
    __shared__ float hb[1024];
    const int tid = threadIdx.x;
    const int b  = blockIdx.x >> 2;
    const int j0 = (blockIdx.x & 3) * 1024;
#pragma unroll
    for (int u = 0; u < 4; ++u) {
        int k = u * 256 + tid;
        hb[k] = hT[k * 64 + b];
    }
    __syncthreads();
#pragma unroll
    for (int rr = 0; rr < 4; ++rr) {
        int j = j0 + rr * 256 + tid;
        const float* wr = Whh + (size_t)j * HH;
        float a = bih[j] + bhh[j];
        for (int k = 0; k < 1024; k += 4) {
            float4 wv = *(const float4*)(wr + k);
            float4 hv = *(const float4*)&hb[k];
            a += hv.x * wv.x + hv.y * wv.y + hv.z * wv.z + hv.w * wv.w;
        }
        hdecg[((size_t)(j >> 10) * 1024 + (j & 1023)) * 64 + b] = a;
    }
}

// ---------------- MFMA decoder (unchanged) ----------------
__global__ __launch_bounds__(256)
void dec_mfma(const _Float16* __restrict__ Adecpk,
              const _Float16* __restrict__ fcWpk,
              const _Float16* __restrict__ Xpk,
              const float* __restrict__ hdecg,
              const float* __restrict__ cT,
              const float* __restrict__ fcb,
              float* __restrict__ out)
{
    __shared__ __align__(16) _Float16 Hn[32 * 64 * 8];   // 32 KB
    __shared__ __align__(16) float outl[16][260];
    const int tid = threadIdx.x;
    const int lane = tid & 63, w = tid >> 6;
    const int t = blockIdx.x >> 2, bq4 = blockIdx.x & 3;
    const int q = lane >> 4, bl = lane & 15;
    const int bg = bq4 * 16 + bl;

    const half8* X8 = (const half8*)Xpk + ((size_t)t * 32 + bq4) * 64 + lane;
    half8 xf[8];
#pragma unroll
    for (int kc2 = 0; kc2 < 8; ++kc2) xf[kc2] = X8[kc2 * 256];

    const half8* AD = (const half8*)Adecpk + lane;
    for (int dqi = 0; dqi < 32; ++dqi) {
        int dq = w * 32 + dqi;
#pragma unroll
        for (int t2 = 0; t2 < 2; ++t2) {
            f32x4 acc = {0.f, 0.f, 0.f, 0.f};
#pragma unroll
            for (int kc2 = 0; kc2 < 8; ++kc2) {
                half8 a = AD[((size_t)(dq * 2 + t2) * 8 + kc2) * 64];
                acc = __builtin_amdgcn_mfma_f32_16x16x32_f16(a, xf[kc2], acc, 0, 0, 0);
            }
            int d = dq * 8 + t2 * 4 + q;
            float cv = cT[d * 64 + bg];
            float pi = acc[0] + hdecg[(size_t)(0 * HH + d) * 64 + bg];
            float pf = acc[1] + hdecg[(size_t)(1 * HH + d) * 64 + bg];
            float pg = acc[2] + hdecg[(size_t)(2 * HH + d) * 64 + bg];
            float po = acc[3] + hdecg[(size_t)(3 * HH + d) * 64 + bg];
            float ig = sigmoidf_(pi), fg = sigmoidf_(pf);
            float gg = tanhf_(pg),    og = sigmoidf_(po);
            float cn = fg * cv + ig * gg;
            float h = og * tanhf_(cn);
            Hn[((d >> 5) * 64 + ((d >> 3) & 3) * 16 + bl) * 8 + (d & 7)] = (_Float16)h;
        }
    }
    __syncthreads();

    const half8* Hn8 = (const half8*)Hn + lane;
    const half8* FW = (const half8*)fcWpk + lane;
#pragma unroll
    for (int oti = 0; oti < 4; ++oti) {
        int ot = w * 4 + oti;
        f32x4 acc = {0.f, 0.f, 0.f, 0.f};
        for (int kc = 0; kc < 32; ++kc) {
            half8 a  = FW[((size_t)ot * 32 + kc) * 64];
            half8 bf = Hn8[kc * 64];
            acc = __builtin_amdgcn_mfma_f32_16x16x32_f16(a, bf, acc, 0, 0, 0);
        }
#pragma unroll
        for (int r = 0; r < 4; ++r) {
            int o = ot * 16 + q * 4 + r;
            outl[bl][o] = acc[r] + fcb[o];
        }
    }
    __syncthreads();

#pragma unroll
    for (int i = 0; i < 16; ++i) {
        int b = bq4 * 16 + i;
        out[((size_t)b * TT_ + t) * OO + tid] = outl[i][tid];
    }
}

extern "C" void kernel_launch(void* const* d_in, const int* in_sizes, int n_in,
                              void* d_out, int out_size, void* d_ws, size_t ws_size,
                              hipStream_t stream) {
    const float* x    = (const float*)d_in[0];
    const float* eWih = (const float*)d_in[1];
    const float* eWhh = (const float*)d_in[2];
    const float* ebih = (const float*)d_in[3];
    const float* ebhh = (const float*)d_in[4];
    const float* dWih = (const float*)d_in[5];
    const float* dWhh = (const float*)d_in[6];
    const float* dbih = (const float*)d_in[7];
    const float* dbhh = (const float*)d_in[8];
    const float* fcW  = (const float*)d_in[9];
    const float* fcb  = (const float*)d_in[10];

    // ws layout (f32 words): hT 65536 | cT 65536 | hdecg 262144 | biasc 4096 |
    // flags 1024 | fp16: Hf0 65536 | Hf1 65536 | Apk 5242880 | Xpk 8388608 |
    // Adecpk 1048576 | fcWpk 262144
    float* ws    = (float*)d_ws;
    float* hT    = ws;
    float* cT    = ws + 65536;
    float* hdecg = ws + 131072;
    float* biasc = ws + 393216;
    int*   flags = (int*)(ws + 397312);
    _Float16* fp  = (_Float16*)(ws + 398336);
    _Float16* Hf0 = fp;
    _Float16* Hf1 = fp + 65536;
    _Float16* Apk = fp + 131072;
    _Float16* Xpk = Apk + 5242880;
    _Float16* Adecpk = Xpk + 8388608;
    _Float16* fcWpk  = Adecpk + 1048576;

    pack_a2<<<dim3(2560), dim3(256), 0, stream>>>(eWhh, eWih, Apk);
    pack_x<<<dim3(4096), dim3(256), 0, stream>>>(x, Xpk);
    pack_bias<<<dim3(16), dim3(256), 0, stream>>>(ebih, ebhh, biasc);
    pack_adec<<<dim3(512), dim3(256), 0, stream>>>(dWih, Adecpk);
    pack_fcw<<<dim3(128), dim3(256), 0, stream>>>(fcW, fcWpk);
    hipMemsetAsync(flags, 0, 1024 * sizeof(int), stream);
    hipMemsetAsync(Hf0, 0, 65536 * sizeof(_Float16), stream);

    enc_persist<<<dim3(256), dim3(256), 0, stream>>>(
        Apk, Xpk, Hf0, Hf1, biasc, cT, hT, flags);

    hdec_kernel<<<dim3(256), dim3(256), 0, stream>>>(hT, dWhh, dbih, dbhh, hdecg);
    dec_mfma<<<dim3(2048), dim3(256), 0, stream>>>(Adecpk, fcWpk, Xpk, hdecg, cT,
                                                   fcb, (float*)d_out);
}

// Round 11
// 3728.237 us; speedup vs baseline: 1.5442x; 1.2353x over previous
//
#include <hip/hip_runtime.h>
#include <hip/hip_bf16.h>

#define BB 64
#define TT_ 512
#define IN_ 256
#define HH 1024
#define G4 4096
#define OO 256

typedef _Float16 half8 __attribute__((ext_vector_type(8)));
typedef float f32x4 __attribute__((ext_vector_type(4)));
typedef unsigned int uint4v __attribute__((ext_vector_type(4)));
typedef int int4v __attribute__((ext_vector_type(4)));

__device__ __forceinline__ float sigmoidf_(float v) {
    return 1.f / (1.f + __expf(-v));
}
__device__ __forceinline__ float tanhf_(float v) {
    float vc = fminf(fmaxf(v, -15.f), 15.f);
    float e = __expf(2.f * vc);
    return (e - 1.f) / (e + 1.f);
}

// ---------------- encoder weight pack ----------------
// Apk[jt(256)][kc(40)][lane(64)][e(8)] fp16; jt = global 4-dim tile (= d>>2).
// Tile rows rD = ddl*4 + g -> MFMA acc[r] of lane (q=l>>4) holds gate r of
// dim jt*4 + q. kc 0..31 = Whh K, kc 32..39 = Wih K.
__global__ __launch_bounds__(256)
void pack_a2(const float* __restrict__ Whh, const float* __restrict__ Wih,
             _Float16* __restrict__ Apk)
{
    int id = blockIdx.x * 256 + threadIdx.x;      // 16B-unit id < 655360
    int dq  = id / 5120;
    int r1  = id - dq * 5120;
    int t2  = r1 / 2560;
    int r2  = r1 - t2 * 2560;
    int kc  = r2 >> 6, l = r2 & 63;
    int rD  = l & 15;
    int g   = rD & 3, ddl = rD >> 2;
    int d   = dq * 8 + t2 * 4 + ddl;
    int j   = g * HH + d;
    int k0  = kc * 32 + ((l >> 4) << 3);
    half8 v;
    if (kc < 32) {
        const float* s = Whh + (size_t)j * HH + k0;
#pragma unroll
        for (int e = 0; e < 8; ++e) v[e] = (_Float16)s[e];
    } else {
        const float* s = Wih + (size_t)j * IN_ + (k0 - 1024);
#pragma unroll
        for (int e = 0; e < 8; ++e) v[e] = (_Float16)s[e];
    }
    ((half8*)Apk)[id] = v;
}

// ---------------- decoder weight pack ----------------
__global__ __launch_bounds__(256)
void pack_adec(const float* __restrict__ Wih, _Float16* __restrict__ Adecpk)
{
    int id = blockIdx.x * 256 + threadIdx.x;      // < 131072
    int dq = id >> 10;
    int r1 = id & 1023;
    int t2 = r1 >> 9;
    int r2 = r1 & 511;
    int kc2 = r2 >> 6, l = r2 & 63;
    int rD = l & 15, g = rD & 3, ddl = rD >> 2;
    int d  = dq * 8 + t2 * 4 + ddl;
    int j  = g * HH + d;
    int k0 = kc2 * 32 + ((l >> 4) << 3);
    const float* s = Wih + (size_t)j * IN_ + k0;
    half8 v;
#pragma unroll
    for (int e = 0; e < 8; ++e) v[e] = (_Float16)s[e];
    ((half8*)Adecpk)[id] = v;
}

// ---------------- FC weight pack ----------------
__global__ __launch_bounds__(256)
void pack_fcw(const float* __restrict__ fcW, _Float16* __restrict__ fcWpk)
{
    int id = blockIdx.x * 256 + threadIdx.x;      // < 32768
    int ot = id >> 11;
    int r  = id & 2047;
    int kc = r >> 6, l = r & 63;
    int o  = ot * 16 + (l & 15);
    int k0 = kc * 32 + ((l >> 4) << 3);
    const float* s = fcW + (size_t)o * HH + k0;
    half8 v;
#pragma unroll
    for (int e = 0; e < 8; ++e) v[e] = (_Float16)s[e];
    ((half8*)fcWpk)[id] = v;
}

// ---------------- x pack ----------------
__global__ __launch_bounds__(256)
void pack_x(const float* __restrict__ x, _Float16* __restrict__ Xpk)
{
    int id = blockIdx.x * 256 + threadIdx.x;  // < 1048576
    int l = id & 63, bt = (id >> 6) & 3, kc2 = (id >> 8) & 7, t = id >> 11;
    int b  = bt * 16 + (l & 15);
    int i0 = kc2 * 32 + ((l >> 4) << 3);
    const float* s = x + ((size_t)b * TT_ + t) * IN_ + i0;
    half8 v;
#pragma unroll
    for (int e = 0; e < 8; ++e) v[e] = (_Float16)s[e];
    ((half8*)Xpk)[id] = v;
}

__global__ __launch_bounds__(256)
void pack_bias(const float* __restrict__ bih, const float* __restrict__ bhh,
               float* __restrict__ biasc)
{
    int j = blockIdx.x * 256 + threadIdx.x;
    if (j < G4) biasc[j] = bih[j] + bhh[j];
}

// ---------------- persistent encoder v7 (R8 memory model + R10 pipeline) ----------------
// grid 256 = (dq16 = bid>>2, grp = bid&3), block 256 (4 waves, 1 WG/CU).
// Wave t4 = one 16-row tile (4 dims x 4 gates) x 16 batches, full K.
// Whh A-frags in LDS (128 KB, once); Wih frags in regs (8, safe).
// Per step: issue sc0sc1 H loads (LLC, no fence needed) -> X-MFMAs from
// prefetched regs under the H shadow -> stage H to LDS -> 32 H-MFMAs ->
// gates in-register -> publish h (sc0sc1 4B) -> per-wave flag (no rendezvous)
// -> wave0 2-deep pipelined poll -> syncthreads release. No HW fences.
__global__ __launch_bounds__(256, 1)
void enc_persist(const _Float16* __restrict__ Apk,
                 const _Float16* __restrict__ Xpk,
                 _Float16* __restrict__ Hbuf0,
                 _Float16* __restrict__ Hbuf1,
                 const float* __restrict__ biasc,
                 float* __restrict__ cT,
                 float* __restrict__ hT,
                 int* __restrict__ flags)
{
    __shared__ __align__(16) _Float16 Ald[4 * 32 * 64 * 8];   // 128 KB
    __shared__ __align__(16) _Float16 Hst[32 * 64 * 8];       // 32 KB
    const int tid  = threadIdx.x;
    const int lane = tid & 63, t4 = tid >> 6;
    const int dq16 = blockIdx.x >> 2, grp = blockIdx.x & 3;
    const int q = lane >> 4, bl = lane & 15;
    const int d = dq16 * 16 + t4 * 4 + q;        // this thread's dim
    const int b = grp * 16 + bl;                 // this thread's batch
    const int jt = dq16 * 4 + t4;                // this wave's A-tile

    // ---- one-time: Whh A-frags -> LDS ----
    {
        const half8* src = (const half8*)Apk + ((size_t)jt * 40) * 64 + lane;
        half8* dst = (half8*)Ald + (size_t)t4 * 32 * 64 + lane;
#pragma unroll
        for (int kc = 0; kc < 32; ++kc) dst[kc * 64] = src[kc * 64];
    }
    // ---- one-time: Wih A-frags -> registers (8 frags, proven safe in R8) ----
    half8 xa[8];
    {
        const half8* src = (const half8*)Apk + ((size_t)jt * 40 + 32) * 64 + lane;
#pragma unroll
        for (int k = 0; k < 8; ++k) xa[k] = src[k * 64];
    }

    float bsum[4];
#pragma unroll
    for (int g = 0; g < 4; ++g) bsum[g] = biasc[g * HH + d];

    const half8* Ald8 = (const half8*)Ald + (size_t)t4 * 32 * 64 + lane;
    const half8* Hld8 = (const half8*)Hst + lane;
    uint4v* Hst16 = (uint4v*)Hst;

    // ---- prologue: xf(0) prefetch (plain cached, 8 x dwordx4) ----
    uint4v xcur[8], xnext[8];
    {
        const uint4v* X16 = (const uint4v*)Xpk + (size_t)grp * 64 + lane;   // t=0
#pragma unroll
        for (int k = 0; k < 8; ++k) {
            asm volatile("global_load_dwordx4 %0, %1, off"
                         : "=v"(xcur[k]) : "v"(X16 + k * 256));
        }
    }

    float c_reg = 0.f, h_last = 0.f;
    __syncthreads();   // A-LDS ready

    for (int t = 0; t < TT_; ++t) {
        const _Float16* Hin = (t & 1) ? Hbuf1 : Hbuf0;
        _Float16* Hout      = (t & 1) ? Hbuf0 : Hbuf1;

        // ---- issue H loads (sc0sc1: LLC-coherent, no fence required) ----
        const uint4v* Hsrc = (const uint4v*)Hin + (size_t)grp * 2048;
        uint4v tmp[8];
#pragma unroll
        for (int i = 0; i < 8; ++i) {
            asm volatile("global_load_dwordx4 %0, %1, off sc0 sc1"
                         : "=v"(tmp[i]) : "v"(Hsrc + i * 256 + tid));
        }
        // retire the xf prologue/prefetch (8 oldest); keep H loads in flight
        asm volatile("s_waitcnt vmcnt(8)" ::: "memory");
        __builtin_amdgcn_sched_barrier(0);

        // ---- X-MFMAs under the H shadow (xcur in regs) ----
        f32x4 acc[4];
#pragma unroll
        for (int i = 0; i < 4; ++i) acc[i] = (f32x4){0.f, 0.f, 0.f, 0.f};
#pragma unroll
        for (int k = 0; k < 8; ++k) {
            half8 bf = __builtin_bit_cast(half8, xcur[k]);
            acc[k & 3] = __builtin_amdgcn_mfma_f32_16x16x32_f16(xa[k], bf, acc[k & 3], 0, 0, 0);
        }

        // ---- H arrived -> stage to LDS ----
        asm volatile("s_waitcnt vmcnt(0)" ::: "memory");
        __builtin_amdgcn_sched_barrier(0);
#pragma unroll
        for (int i = 0; i < 8; ++i) Hst16[i * 256 + tid] = tmp[i];

        // ---- prefetch xf(t+1) (plain cached; retires at the publish drain) ----
        {
            int tn = (t + 1 < TT_) ? t + 1 : t;
            const uint4v* Xn = (const uint4v*)Xpk + ((size_t)tn * 32 + grp) * 64 + lane;
#pragma unroll
            for (int k = 0; k < 8; ++k) {
                asm volatile("global_load_dwordx4 %0, %1, off"
                             : "=v"(xnext[k]) : "v"(Xn + k * 256));
            }
        }
        __syncthreads();   // H-LDS ready

        // ---- 32 H-MFMAs (A from LDS, B from LDS) ----
#pragma unroll
        for (int kc = 0; kc < 32; ++kc) {
            half8 a  = Ald8[kc * 64];
            half8 bf = Hld8[kc * 64];
            acc[kc & 3] = __builtin_amdgcn_mfma_f32_16x16x32_f16(a, bf, acc[kc & 3], 0, 0, 0);
        }

        // ---- gates fully in-register ----
        float pi = acc[0][0] + acc[1][0] + acc[2][0] + acc[3][0] + bsum[0];
        float pf = acc[0][1] + acc[1][1] + acc[2][1] + acc[3][1] + bsum[1];
        float pg = acc[0][2] + acc[1][2] + acc[2][2] + acc[3][2] + bsum[2];
        float po = acc[0][3] + acc[1][3] + acc[2][3] + acc[3][3] + bsum[3];
        float ig = sigmoidf_(pi), fg = sigmoidf_(pf);
        float gg = tanhf_(pg),    og = sigmoidf_(po);
        c_reg = fg * c_reg + ig * gg;
        float h = og * tanhf_(c_reg);
        h_last = h;

        // ---- publish h (B-frag layout, pair dims via shfl, 4B sc0sc1) ----
        float hp = __shfl_xor(h, 16);    // partner q^1 -> dim d^1
        if (!(q & 1)) {
            _Float16 h0 = (_Float16)h, h1 = (_Float16)hp;
            unsigned int pk = (unsigned int)__builtin_bit_cast(unsigned short, h0) |
                              ((unsigned int)__builtin_bit_cast(unsigned short, h1) << 16);
            unsigned int idx = ((unsigned)grp * 2048 + ((unsigned)d >> 5) * 64 +
                                (((unsigned)d >> 3) & 3) * 16 + bl) * 8 + (d & 7);
            asm volatile("global_store_dword %0, %1, off sc0 sc1"
                         :: "v"((unsigned int*)&Hout[idx]), "v"(pk) : "memory");
        }
        // drain this wave's h stores (+ retires xnext prefetch)
        asm volatile("s_waitcnt vmcnt(0)" ::: "memory");
        __builtin_amdgcn_sched_barrier(0);

        // rotate xf regs
#pragma unroll
        for (int k = 0; k < 8; ++k) xcur[k] = xnext[k];

        if (t < TT_ - 1) {
            // ---- per-wave arrival flag (no WG rendezvous before signal) ----
            if (lane == 0) {
                int val = t + 1;
                asm volatile("global_store_dword %0, %1, off sc0 sc1"
                             :: "v"(flags + grp * 256 + dq16 * 4 + t4), "v"(val)
                             : "memory");
            }
            // ---- wave0: 2-deep pipelined poll over the group's 256 flags ----
            if (t4 == 0) {
                const int* fp4 = flags + grp * 256 + lane * 4;
                int tgt = t + 1;
                int4v f0, f1;
                asm volatile("global_load_dwordx4 %0, %2, off sc0 sc1\n\t"
                             "s_sleep 1\n\t"
                             "global_load_dwordx4 %1, %2, off sc0 sc1"
                             : "=&v"(f0), "=v"(f1) : "v"(fp4) : "memory");
                for (;;) {
                    asm volatile("s_waitcnt vmcnt(1)" ::: "memory");
                    __builtin_amdgcn_sched_barrier(0);
                    if (__all(min(min(f0.x, f0.y), min(f0.z, f0.w)) >= tgt)) break;
                    asm volatile("global_load_dwordx4 %0, %1, off sc0 sc1"
                                 : "=v"(f0) : "v"(fp4) : "memory");
                    __builtin_amdgcn_s_sleep(1);
                    asm volatile("s_waitcnt vmcnt(1)" ::: "memory");
                    __builtin_amdgcn_sched_barrier(0);
                    if (__all(min(min(f1.x, f1.y), min(f1.z, f1.w)) >= tgt)) break;
                    asm volatile("global_load_dwordx4 %0, %1, off sc0 sc1"
                                 : "=v"(f1) : "v"(fp4) : "memory");
                    __builtin_amdgcn_s_sleep(1);
                }
                // retire stragglers while keeping f0/f1 registers alive
                asm volatile("s_waitcnt vmcnt(0)" :: "v"(f0), "v"(f1) : "memory");
            }
            __syncthreads();   // release all waves; Hst free to overwrite
        }
    }

    // ---- final state for decoder ----
    cT[d * 64 + b] = c_reg;
    hT[d * 64 + b] = h_last;
}

// ---------------- hdecg = h_final @ dec_Whh^T + biases (gate-major out) ----------------
__global__ __launch_bounds__(256)
void hdec_kernel(const float* __restrict__ hT, const float* __restrict__ Whh,
                 const float* __restrict__ bih, const float* __restrict__ bhh,
                 float* __restrict__ hdecg)
{
    __shared__ float hb[1024];
    const int tid = threadIdx.x;
    const int b  = blockIdx.x >> 2;
    const int j0 = (blockIdx.x & 3) * 1024;
#pragma unroll
    for (int u = 0; u < 4; ++u) {
        int k = u * 256 + tid;
        hb[k] = hT[k * 64 + b];
    }
    __syncthreads();
#pragma unroll
    for (int rr = 0; rr < 4; ++rr) {
        int j = j0 + rr * 256 + tid;
        const float* wr = Whh + (size_t)j * HH;
        float a = bih[j] + bhh[j];
        for (int k = 0; k < 1024; k += 4) {
            float4 wv = *(const float4*)(wr + k);
            float4 hv = *(const float4*)&hb[k];
            a += hv.x * wv.x + hv.y * wv.y + hv.z * wv.z + hv.w * wv.w;
        }
        hdecg[((size_t)(j >> 10) * 1024 + (j & 1023)) * 64 + b] = a;
    }
}

// ---------------- MFMA decoder (unchanged) ----------------
__global__ __launch_bounds__(256)
void dec_mfma(const _Float16* __restrict__ Adecpk,
              const _Float16* __restrict__ fcWpk,
              const _Float16* __restrict__ Xpk,
              const float* __restrict__ hdecg,
              const float* __restrict__ cT,
              const float* __restrict__ fcb,
              float* __restrict__ out)
{
    __shared__ __align__(16) _Float16 Hn[32 * 64 * 8];   // 32 KB
    __shared__ __align__(16) float outl[16][260];
    const int tid = threadIdx.x;
    const int lane = tid & 63, w = tid >> 6;
    const int t = blockIdx.x >> 2, bq4 = blockIdx.x & 3;
    const int q = lane >> 4, bl = lane & 15;
    const int bg = bq4 * 16 + bl;

    const half8* X8 = (const half8*)Xpk + ((size_t)t * 32 + bq4) * 64 + lane;
    half8 xf[8];
#pragma unroll
    for (int kc2 = 0; kc2 < 8; ++kc2) xf[kc2] = X8[kc2 * 256];

    const half8* AD = (const half8*)Adecpk + lane;
    for (int dqi = 0; dqi < 32; ++dqi) {
        int dq = w * 32 + dqi;
#pragma unroll
        for (int t2 = 0; t2 < 2; ++t2) {
            f32x4 acc = {0.f, 0.f, 0.f, 0.f};
#pragma unroll
            for (int kc2 = 0; kc2 < 8; ++kc2) {
                half8 a = AD[((size_t)(dq * 2 + t2) * 8 + kc2) * 64];
                acc = __builtin_amdgcn_mfma_f32_16x16x32_f16(a, xf[kc2], acc, 0, 0, 0);
            }
            int d = dq * 8 + t2 * 4 + q;
            float cv = cT[d * 64 + bg];
            float pi = acc[0] + hdecg[(size_t)(0 * HH + d) * 64 + bg];
            float pf = acc[1] + hdecg[(size_t)(1 * HH + d) * 64 + bg];
            float pg = acc[2] + hdecg[(size_t)(2 * HH + d) * 64 + bg];
            float po = acc[3] + hdecg[(size_t)(3 * HH + d) * 64 + bg];
            float ig = sigmoidf_(pi), fg = sigmoidf_(pf);
            float gg = tanhf_(pg),    og = sigmoidf_(po);
            float cn = fg * cv + ig * gg;
            float h = og * tanhf_(cn);
            Hn[((d >> 5) * 64 + ((d >> 3) & 3) * 16 + bl) * 8 + (d & 7)] = (_Float16)h;
        }
    }
    __syncthreads();

    const half8* Hn8 = (const half8*)Hn + lane;
    const half8* FW = (const half8*)fcWpk + lane;
#pragma unroll
    for (int oti = 0; oti < 4; ++oti) {
        int ot = w * 4 + oti;
        f32x4 acc = {0.f, 0.f, 0.f, 0.f};
        for (int kc = 0; kc < 32; ++kc) {
            half8 a  = FW[((size_t)ot * 32 + kc) * 64];
            half8 bf = Hn8[kc * 64];
            acc = __builtin_amdgcn_mfma_f32_16x16x32_f16(a, bf, acc, 0, 0, 0);
        }
#pragma unroll
        for (int r = 0; r < 4; ++r) {
            int o = ot * 16 + q * 4 + r;
            outl[bl][o] = acc[r] + fcb[o];
        }
    }
    __syncthreads();

#pragma unroll
    for (int i = 0; i < 16; ++i) {
        int b = bq4 * 16 + i;
        out[((size_t)b * TT_ + t) * OO + tid] = outl[i][tid];
    }
}

extern "C" void kernel_launch(void* const* d_in, const int* in_sizes, int n_in,
                              void* d_out, int out_size, void* d_ws, size_t ws_size,
                              hipStream_t stream) {
    const float* x    = (const float*)d_in[0];
    const float* eWih = (const float*)d_in[1];
    const float* eWhh = (const float*)d_in[2];
    const float* ebih = (const float*)d_in[3];
    const float* ebhh = (const float*)d_in[4];
    const float* dWih = (const float*)d_in[5];
    const float* dWhh = (const float*)d_in[6];
    const float* dbih = (const float*)d_in[7];
    const float* dbhh = (const float*)d_in[8];
    const float* fcW  = (const float*)d_in[9];
    const float* fcb  = (const float*)d_in[10];

    // ws layout (f32 words): hT 65536 | cT 65536 | hdecg 262144 | biasc 4096 |
    // flags 1024 | fp16: Hf0 65536 | Hf1 65536 | Apk 5242880 | Xpk 8388608 |
    // Adecpk 1048576 | fcWpk 262144
    float* ws    = (float*)d_ws;
    float* hT    = ws;
    float* cT    = ws + 65536;
    float* hdecg = ws + 131072;
    float* biasc = ws + 393216;
    int*   flags = (int*)(ws + 397312);
    _Float16* fp  = (_Float16*)(ws + 398336);
    _Float16* Hf0 = fp;
    _Float16* Hf1 = fp + 65536;
    _Float16* Apk = fp + 131072;
    _Float16* Xpk = Apk + 5242880;
    _Float16* Adecpk = Xpk + 8388608;
    _Float16* fcWpk  = Adecpk + 1048576;

    pack_a2<<<dim3(2560), dim3(256), 0, stream>>>(eWhh, eWih, Apk);
    pack_x<<<dim3(4096), dim3(256), 0, stream>>>(x, Xpk);
    pack_bias<<<dim3(16), dim3(256), 0, stream>>>(ebih, ebhh, biasc);
    pack_adec<<<dim3(512), dim3(256), 0, stream>>>(dWih, Adecpk);
    pack_fcw<<<dim3(128), dim3(256), 0, stream>>>(fcW, fcWpk);
    hipMemsetAsync(flags, 0, 1024 * sizeof(int), stream);
    hipMemsetAsync(Hf0, 0, 65536 * sizeof(_Float16), stream);

    enc_persist<<<dim3(256), dim3(256), 0, stream>>>(
        Apk, Xpk, Hf0, Hf1, biasc, cT, hT, flags);

    hdec_kernel<<<dim3(256), dim3(256), 0, stream>>>(hT, dWhh, dbih, dbhh, hdecg);
    dec_mfma<<<dim3(2048), dim3(256), 0, stream>>>(Adecpk, fcWpk, Xpk, hdecg, cT,
                                                   fcb, (float*)d_out);
}

// Round 13
// 2378.936 us; speedup vs baseline: 2.4201x; 1.5672x over previous
//
#include <hip/hip_runtime.h>
#include <hip/hip_bf16.h>

#define BB 64
#define TT_ 512
#define IN_ 256
#define HH 1024
#define G4 4096
#define OO 256

typedef _Float16 half8 __attribute__((ext_vector_type(8)));
typedef float f32x4 __attribute__((ext_vector_type(4)));
typedef unsigned int uint4v __attribute__((ext_vector_type(4)));

__device__ __forceinline__ float sigmoidf_(float v) {
    return 1.f / (1.f + __expf(-v));
}
__device__ __forceinline__ float tanhf_(float v) {
    float vc = fminf(fmaxf(v, -15.f), 15.f);
    float e = __expf(2.f * vc);
    return (e - 1.f) / (e + 1.f);
}

// ---------------- encoder weight pack ----------------
// Apk[jt(256)][kc(40)][lane(64)][e(8)] fp16; jt = global 4-dim tile (= d>>2).
// Tile rows rD = ddl*4 + g -> MFMA acc[r] of lane (q=l>>4) holds gate r of
// dim jt*4 + q. kc 0..31 = Whh K, kc 32..39 = Wih K.
__global__ __launch_bounds__(256)
void pack_a2(const float* __restrict__ Whh, const float* __restrict__ Wih,
             _Float16* __restrict__ Apk)
{
    int id = blockIdx.x * 256 + threadIdx.x;      // 16B-unit id < 655360
    int dq  = id / 5120;
    int r1  = id - dq * 5120;
    int t2  = r1 / 2560;
    int r2  = r1 - t2 * 2560;
    int kc  = r2 >> 6, l = r2 & 63;
    int rD  = l & 15;
    int g   = rD & 3, ddl = rD >> 2;
    int d   = dq * 8 + t2 * 4 + ddl;
    int j   = g * HH + d;
    int k0  = kc * 32 + ((l >> 4) << 3);
    half8 v;
    if (kc < 32) {
        const float* s = Whh + (size_t)j * HH + k0;
#pragma unroll
        for (int e = 0; e < 8; ++e) v[e] = (_Float16)s[e];
    } else {
        const float* s = Wih + (size_t)j * IN_ + (k0 - 1024);
#pragma unroll
        for (int e = 0; e < 8; ++e) v[e] = (_Float16)s[e];
    }
    ((half8*)Apk)[id] = v;
}

// ---------------- decoder weight pack ----------------
__global__ __launch_bounds__(256)
void pack_adec(const float* __restrict__ Wih, _Float16* __restrict__ Adecpk)
{
    int id = blockIdx.x * 256 + threadIdx.x;      // < 131072
    int dq = id >> 10;
    int r1 = id & 1023;
    int t2 = r1 >> 9;
    int r2 = r1 & 511;
    int kc2 = r2 >> 6, l = r2 & 63;
    int rD = l & 15, g = rD & 3, ddl = rD >> 2;
    int d  = dq * 8 + t2 * 4 + ddl;
    int j  = g * HH + d;
    int k0 = kc2 * 32 + ((l >> 4) << 3);
    const float* s = Wih + (size_t)j * IN_ + k0;
    half8 v;
#pragma unroll
    for (int e = 0; e < 8; ++e) v[e] = (_Float16)s[e];
    ((half8*)Adecpk)[id] = v;
}

// ---------------- FC weight pack ----------------
__global__ __launch_bounds__(256)
void pack_fcw(const float* __restrict__ fcW, _Float16* __restrict__ fcWpk)
{
    int id = blockIdx.x * 256 + threadIdx.x;      // < 32768
    int ot = id >> 11;
    int r  = id & 2047;
    int kc = r >> 6, l = r & 63;
    int o  = ot * 16 + (l & 15);
    int k0 = kc * 32 + ((l >> 4) << 3);
    const float* s = fcW + (size_t)o * HH + k0;
    half8 v;
#pragma unroll
    for (int e = 0; e < 8; ++e) v[e] = (_Float16)s[e];
    ((half8*)fcWpk)[id] = v;
}

// ---------------- x pack ----------------
__global__ __launch_bounds__(256)
void pack_x(const float* __restrict__ x, _Float16* __restrict__ Xpk)
{
    int id = blockIdx.x * 256 + threadIdx.x;  // < 1048576
    int l = id & 63, bt = (id >> 6) & 3, kc2 = (id >> 8) & 7, t = id >> 11;
    int b  = bt * 16 + (l & 15);
    int i0 = kc2 * 32 + ((l >> 4) << 3);
    const float* s = x + ((size_t)b * TT_ + t) * IN_ + i0;
    half8 v;
#pragma unroll
    for (int e = 0; e < 8; ++e) v[e] = (_Float16)s[e];
    ((half8*)Xpk)[id] = v;
}

__global__ __launch_bounds__(256)
void pack_bias(const float* __restrict__ bih, const float* __restrict__ bhh,
               float* __restrict__ biasc)
{
    int j = blockIdx.x * 256 + threadIdx.x;
    if (j < G4) biasc[j] = bih[j] + bhh[j];
}

// ---------------- persistent encoder v8b: dataflow (poison-tagged h), stride fixed ----------------
// grid 256 = (dq16 = bid>>2, grp = bid&3), block 256 (4 waves, 1 WG/CU).
// R8 geometry: wave t4 = 16-row tile (4 dims x 4 gates) x 16 batches; Whh in
// LDS (128 KB once), Wih frags in regs. NO flags/barriers: h slots carry their
// own readiness (0xFFFFFFFF poison = not written; h is never NaN). 64 slots of
// 65536 fp16 (= 8192 uint4v; R12 bug was 4096 here); slot = t&63; rolling
// re-poison of slot (t+8)&63 after each publish (56-step margin vs <=1 drift).
__global__ __launch_bounds__(256, 1)
void enc_persist(const _Float16* __restrict__ Apk,
                 const _Float16* __restrict__ Xpk,
                 _Float16* __restrict__ Hbuf,
                 const float* __restrict__ biasc,
                 float* __restrict__ cT,
                 float* __restrict__ hT)
{
    __shared__ __align__(16) _Float16 Ald[4 * 32 * 64 * 8];   // 128 KB
    __shared__ __align__(16) _Float16 Hst[32 * 64 * 8];       // 32 KB
    const int tid  = threadIdx.x;
    const int lane = tid & 63, t4 = tid >> 6;
    const int dq16 = blockIdx.x >> 2, grp = blockIdx.x & 3;
    const int q = lane >> 4, bl = lane & 15;
    const int d = dq16 * 16 + t4 * 4 + q;        // this thread's dim
    const int b = grp * 16 + bl;                 // this thread's batch
    const int jt = dq16 * 4 + t4;                // this wave's A-tile

    // ---- one-time: Whh A-frags -> LDS ----
    {
        const half8* src = (const half8*)Apk + ((size_t)jt * 40) * 64 + lane;
        half8* dst = (half8*)Ald + (size_t)t4 * 32 * 64 + lane;
#pragma unroll
        for (int kc = 0; kc < 32; ++kc) dst[kc * 64] = src[kc * 64];
    }
    // ---- one-time: Wih A-frags -> registers (8 frags) ----
    half8 xa[8];
    {
        const half8* src = (const half8*)Apk + ((size_t)jt * 40 + 32) * 64 + lane;
#pragma unroll
        for (int k = 0; k < 8; ++k) xa[k] = src[k * 64];
    }

    float bsum[4];
#pragma unroll
    for (int g = 0; g < 4; ++g) bsum[g] = biasc[g * HH + d];

    const half8* Ald8 = (const half8*)Ald + (size_t)t4 * 32 * 64 + lane;
    const half8* Hld8 = (const half8*)Hst + lane;
    uint4v* Hst16 = (uint4v*)Hst;

    // publish half-index within a slot (pair of dims d, d^1 packed as u32),
    // in fp16 units; slot stride = 65536 fp16
    const unsigned int pidx = ((unsigned)grp * 2048 + ((unsigned)d >> 5) * 64 +
                               (((unsigned)d >> 3) & 3) * 16 + bl) * 8 + (d & 7);

    float c_reg = 0.f, h_last = 0.f;
    __syncthreads();   // A-LDS ready

    for (int t = 0; t < TT_; ++t) {
        const int sIn  = (t - 1) & 63;
        const int sOut = t & 63;
        const int sPoi = (t + 8) & 63;

        f32x4 acc[4];
#pragma unroll
        for (int i = 0; i < 4; ++i) acc[i] = (f32x4){0.f, 0.f, 0.f, 0.f};

        // ---- X B-frags (plain cached; retire under the H poll wait) ----
        const half8* X8 = (const half8*)Xpk + ((size_t)t * 32 + grp) * 64 + lane;
        half8 xf[8];

        if (t > 0) {
            // ---- issue H loads for slot sIn (sc0sc1 -> LLC-coherent) ----
            // slot = 8192 uint4v (65536 fp16); group slice = 2048 uint4v
            const uint4v* Hsrc = (const uint4v*)Hbuf + (size_t)sIn * 8192 +
                                 (size_t)grp * 2048;
            uint4v tmp[8];
#pragma unroll
            for (int i = 0; i < 8; ++i) {
                asm volatile("global_load_dwordx4 %0, %1, off sc0 sc1"
                             : "=v"(tmp[i]) : "v"(Hsrc + i * 256 + tid));
            }
#pragma unroll
            for (int k = 0; k < 8; ++k) xf[k] = X8[k * 256];

            // ---- poll: data-readiness check (u32 != poison), retry ----
            for (;;) {
                asm volatile("s_waitcnt vmcnt(0)" ::: "memory");
                __builtin_amdgcn_sched_barrier(0);
                int ok = 1;
#pragma unroll
                for (int i = 0; i < 8; ++i) {
                    ok &= (tmp[i].x != 0xFFFFFFFFu) & (tmp[i].y != 0xFFFFFFFFu) &
                          (tmp[i].z != 0xFFFFFFFFu) & (tmp[i].w != 0xFFFFFFFFu);
                }
                if (__all(ok)) break;
#pragma unroll
                for (int i = 0; i < 8; ++i) {
                    asm volatile("global_load_dwordx4 %0, %1, off sc0 sc1"
                                 : "=v"(tmp[i]) : "v"(Hsrc + i * 256 + tid));
                }
                __builtin_amdgcn_s_sleep(1);
            }

            // ---- stage H to LDS ----
#pragma unroll
            for (int i = 0; i < 8; ++i) Hst16[i * 256 + tid] = tmp[i];
            __syncthreads();   // H-LDS ready

            // ---- 8 X-MFMAs + 32 H-MFMAs, 4 acc chains ----
#pragma unroll
            for (int k = 0; k < 8; ++k)
                acc[k & 3] = __builtin_amdgcn_mfma_f32_16x16x32_f16(xa[k], xf[k], acc[k & 3], 0, 0, 0);
#pragma unroll
            for (int kc = 0; kc < 32; ++kc) {
                half8 a  = Ald8[kc * 64];
                half8 bf = Hld8[kc * 64];
                acc[kc & 3] = __builtin_amdgcn_mfma_f32_16x16x32_f16(a, bf, acc[kc & 3], 0, 0, 0);
            }
        } else {
            // t = 0: h(-1) = 0 -> X contribution only
#pragma unroll
            for (int k = 0; k < 8; ++k) xf[k] = X8[k * 256];
#pragma unroll
            for (int k = 0; k < 8; ++k)
                acc[k & 3] = __builtin_amdgcn_mfma_f32_16x16x32_f16(xa[k], xf[k], acc[k & 3], 0, 0, 0);
        }

        // ---- gates fully in-register ----
        float pi = acc[0][0] + acc[1][0] + acc[2][0] + acc[3][0] + bsum[0];
        float pf = acc[0][1] + acc[1][1] + acc[2][1] + acc[3][1] + bsum[1];
        float pg = acc[0][2] + acc[1][2] + acc[2][2] + acc[3][2] + bsum[2];
        float po = acc[0][3] + acc[1][3] + acc[2][3] + acc[3][3] + bsum[3];
        float ig = sigmoidf_(pi), fg = sigmoidf_(pf);
        float gg = tanhf_(pg),    og = sigmoidf_(po);
        c_reg = fg * c_reg + ig * gg;
        float h = og * tanhf_(c_reg);
        h_last = h;

        // ---- publish h(t) to slot sOut + rolling re-poison of slot sPoi ----
        float hp = __shfl_xor(h, 16);    // partner q^1 -> dim d^1
        if (t < TT_ - 1 && !(q & 1)) {
            _Float16 h0 = (_Float16)h, h1 = (_Float16)hp;
            unsigned int pk = (unsigned int)__builtin_bit_cast(unsigned short, h0) |
                              ((unsigned int)__builtin_bit_cast(unsigned short, h1) << 16);
            unsigned int* po_ = (unsigned int*)(Hbuf + (size_t)sOut * 65536 + pidx);
            asm volatile("global_store_dword %0, %1, off sc0 sc1"
                         :: "v"(po_), "v"(pk) : "memory");
            unsigned int* pz = (unsigned int*)(Hbuf + (size_t)sPoi * 65536 + pidx);
            unsigned int poison = 0xFFFFFFFFu;
            asm volatile("global_store_dword %0, %1, off sc0 sc1"
                         :: "v"(pz), "v"(poison) : "memory");
        }
        // no drain, no flags: next step's poll vmcnt(0) retires these stores

        if (t < TT_ - 1) __syncthreads();   // protect Hst before next staging
    }

    // ---- final state for decoder ----
    cT[d * 64 + b] = c_reg;
    hT[d * 64 + b] = h_last;
}

// ---------------- hdecg = h_final @ dec_Whh^T + biases (gate-major out) ----------------
__global__ __launch_bounds__(256)
void hdec_kernel(const float* __restrict__ hT, const float* __restrict__ Whh,
                 const float* __restrict__ bih, const float* __restrict__ bhh,
                 float* __restrict__ hdecg)
{
    __shared__ float hb[1024];
    const int tid = threadIdx.x;
    const int b  = blockIdx.x >> 2;
    const int j0 = (blockIdx.x & 3) * 1024;
#pragma unroll
    for (int u = 0; u < 4; ++u) {
        int k = u * 256 + tid;
        hb[k] = hT[k * 64 + b];
    }
    __syncthreads();
#pragma unroll
    for (int rr = 0; rr < 4; ++rr) {
        int j = j0 + rr * 256 + tid;
        const float* wr = Whh + (size_t)j * HH;
        float a = bih[j] + bhh[j];
        for (int k = 0; k < 1024; k += 4) {
            float4 wv = *(const float4*)(wr + k);
            float4 hv = *(const float4*)&hb[k];
            a += hv.x * wv.x + hv.y * wv.y + hv.z * wv.z + hv.w * wv.w;
        }
        hdecg[((size_t)(j >> 10) * 1024 + (j & 1023)) * 64 + b] = a;
    }
}

// ---------------- MFMA decoder (unchanged) ----------------
__global__ __launch_bounds__(256)
void dec_mfma(const _Float16* __restrict__ Adecpk,
              const _Float16* __restrict__ fcWpk,
              const _Float16* __restrict__ Xpk,
              const float* __restrict__ hdecg,
              const float* __restrict__ cT,
              const float* __restrict__ fcb,
              float* __restrict__ out)
{
    __shared__ __align__(16) _Float16 Hn[32 * 64 * 8];   // 32 KB
    __shared__ __align__(16) float outl[16][260];
    const int tid = threadIdx.x;
    const int lane = tid & 63, w = tid >> 6;
    const int t = blockIdx.x >> 2, bq4 = blockIdx.x & 3;
    const int q = lane >> 4, bl = lane & 15;
    const int bg = bq4 * 16 + bl;

    const half8* X8 = (const half8*)Xpk + ((size_t)t * 32 + bq4) * 64 + lane;
    half8 xf[8];
#pragma unroll
    for (int kc2 = 0; kc2 < 8; ++kc2) xf[kc2] = X8[kc2 * 256];

    const half8* AD = (const half8*)Adecpk + lane;
    for (int dqi = 0; dqi < 32; ++dqi) {
        int dq = w * 32 + dqi;
#pragma unroll
        for (int t2 = 0; t2 < 2; ++t2) {
            f32x4 acc = {0.f, 0.f, 0.f, 0.f};
#pragma unroll
            for (int kc2 = 0; kc2 < 8; ++kc2) {
                half8 a = AD[((size_t)(dq * 2 + t2) * 8 + kc2) * 64];
                acc = __builtin_amdgcn_mfma_f32_16x16x32_f16(a, xf[kc2], acc, 0, 0, 0);
            }
            int d = dq * 8 + t2 * 4 + q;
            float cv = cT[d * 64 + bg];
            float pi = acc[0] + hdecg[(size_t)(0 * HH + d) * 64 + bg];
            float pf = acc[1] + hdecg[(size_t)(1 * HH + d) * 64 + bg];
            float pg = acc[2] + hdecg[(size_t)(2 * HH + d) * 64 + bg];
            float po = acc[3] + hdecg[(size_t)(3 * HH + d) * 64 + bg];
            float ig = sigmoidf_(pi), fg = sigmoidf_(pf);
            float gg = tanhf_(pg),    og = sigmoidf_(po);
            float cn = fg * cv + ig * gg;
            float h = og * tanhf_(cn);
            Hn[((d >> 5) * 64 + ((d >> 3) & 3) * 16 + bl) * 8 + (d & 7)] = (_Float16)h;
        }
    }
    __syncthreads();

    const half8* Hn8 = (const half8*)Hn + lane;
    const half8* FW = (const half8*)fcWpk + lane;
#pragma unroll
    for (int oti = 0; oti < 4; ++oti) {
        int ot = w * 4 + oti;
        f32x4 acc = {0.f, 0.f, 0.f, 0.f};
        for (int kc = 0; kc < 32; ++kc) {
            half8 a  = FW[((size_t)ot * 32 + kc) * 64];
            half8 bf = Hn8[kc * 64];
            acc = __builtin_amdgcn_mfma_f32_16x16x32_f16(a, bf, acc, 0, 0, 0);
        }
#pragma unroll
        for (int r = 0; r < 4; ++r) {
            int o = ot * 16 + q * 4 + r;
            outl[bl][o] = acc[r] + fcb[o];
        }
    }
    __syncthreads();

#pragma unroll
    for (int i = 0; i < 16; ++i) {
        int b = bq4 * 16 + i;
        out[((size_t)b * TT_ + t) * OO + tid] = outl[i][tid];
    }
}

extern "C" void kernel_launch(void* const* d_in, const int* in_sizes, int n_in,
                              void* d_out, int out_size, void* d_ws, size_t ws_size,
                              hipStream_t stream) {
    const float* x    = (const float*)d_in[0];
    const float* eWih = (const float*)d_in[1];
    const float* eWhh = (const float*)d_in[2];
    const float* ebih = (const float*)d_in[3];
    const float* ebhh = (const float*)d_in[4];
    const float* dWih = (const float*)d_in[5];
    const float* dWhh = (const float*)d_in[6];
    const float* dbih = (const float*)d_in[7];
    const float* dbhh = (const float*)d_in[8];
    const float* fcW  = (const float*)d_in[9];
    const float* fcb  = (const float*)d_in[10];

    // ws layout (f32 words): hT 65536 | cT 65536 | hdecg 262144 | biasc 4096 |
    // then fp16: Hbuf 64 slots x 65536 = 4194304 | Apk 5242880 | Xpk 8388608 |
    // Adecpk 1048576 | fcWpk 262144   (~40 MB total)
    float* ws    = (float*)d_ws;
    float* hT    = ws;
    float* cT    = ws + 65536;
    float* hdecg = ws + 131072;
    float* biasc = ws + 393216;
    _Float16* fp  = (_Float16*)(ws + 397568);
    _Float16* Hbuf = fp;
    _Float16* Apk  = fp + 4194304;
    _Float16* Xpk  = Apk + 5242880;
    _Float16* Adecpk = Xpk + 8388608;
    _Float16* fcWpk  = Adecpk + 1048576;

    pack_a2<<<dim3(2560), dim3(256), 0, stream>>>(eWhh, eWih, Apk);
    pack_x<<<dim3(4096), dim3(256), 0, stream>>>(x, Xpk);
    pack_bias<<<dim3(16), dim3(256), 0, stream>>>(ebih, ebhh, biasc);
    pack_adec<<<dim3(512), dim3(256), 0, stream>>>(dWih, Adecpk);
    pack_fcw<<<dim3(128), dim3(256), 0, stream>>>(fcW, fcWpk);
    // poison all 64 h slots (0xFF bytes -> u32 0xFFFFFFFF = fp16 NaN pair)
    hipMemsetAsync(Hbuf, 0xFF, (size_t)4194304 * sizeof(_Float16), stream);

    enc_persist<<<dim3(256), dim3(256), 0, stream>>>(
        Apk, Xpk, Hbuf, biasc, cT, hT);

    hdec_kernel<<<dim3(256), dim3(256), 0, stream>>>(hT, dWhh, dbih, dbhh, hdecg);
    dec_mfma<<<dim3(2048), dim3(256), 0, stream>>>(Adecpk, fcWpk, Xpk, hdecg, cT,
                                                   fcb, (float*)d_out);
}

// Round 14
// 2339.776 us; speedup vs baseline: 2.4606x; 1.0167x over previous
//
#include <hip/hip_runtime.h>
#include <hip/hip_bf16.h>

#define BB 64
#define TT_ 512
#define IN_ 256
#define HH 1024
#define G4 4096
#define OO 256

typedef _Float16 half8 __attribute__((ext_vector_type(8)));
typedef float f32x4 __attribute__((ext_vector_type(4)));
typedef unsigned int uint4v __attribute__((ext_vector_type(4)));

__device__ __forceinline__ float sigmoidf_(float v) {
    return 1.f / (1.f + __expf(-v));
}
__device__ __forceinline__ float tanhf_(float v) {
    float vc = fminf(fmaxf(v, -15.f), 15.f);
    float e = __expf(2.f * vc);
    return (e - 1.f) / (e + 1.f);
}

// ---------------- encoder weight pack ----------------
// Apk[jt(256)][kc(40)][lane(64)][e(8)] fp16; jt = global 4-dim tile (= d>>2).
// Tile rows rD = ddl*4 + g -> MFMA acc[r] of lane (q=l>>4) holds gate r of
// dim jt*4 + q. kc 0..31 = Whh K, kc 32..39 = Wih K.
__global__ __launch_bounds__(256)
void pack_a2(const float* __restrict__ Whh, const float* __restrict__ Wih,
             _Float16* __restrict__ Apk)
{
    int id = blockIdx.x * 256 + threadIdx.x;      // 16B-unit id < 655360
    int dq  = id / 5120;
    int r1  = id - dq * 5120;
    int t2  = r1 / 2560;
    int r2  = r1 - t2 * 2560;
    int kc  = r2 >> 6, l = r2 & 63;
    int rD  = l & 15;
    int g   = rD & 3, ddl = rD >> 2;
    int d   = dq * 8 + t2 * 4 + ddl;
    int j   = g * HH + d;
    int k0  = kc * 32 + ((l >> 4) << 3);
    half8 v;
    if (kc < 32) {
        const float* s = Whh + (size_t)j * HH + k0;
#pragma unroll
        for (int e = 0; e < 8; ++e) v[e] = (_Float16)s[e];
    } else {
        const float* s = Wih + (size_t)j * IN_ + (k0 - 1024);
#pragma unroll
        for (int e = 0; e < 8; ++e) v[e] = (_Float16)s[e];
    }
    ((half8*)Apk)[id] = v;
}

// ---------------- decoder weight pack ----------------
__global__ __launch_bounds__(256)
void pack_adec(const float* __restrict__ Wih, _Float16* __restrict__ Adecpk)
{
    int id = blockIdx.x * 256 + threadIdx.x;      // < 131072
    int dq = id >> 10;
    int r1 = id & 1023;
    int t2 = r1 >> 9;
    int r2 = r1 & 511;
    int kc2 = r2 >> 6, l = r2 & 63;
    int rD = l & 15, g = rD & 3, ddl = rD >> 2;
    int d  = dq * 8 + t2 * 4 + ddl;
    int j  = g * HH + d;
    int k0 = kc2 * 32 + ((l >> 4) << 3);
    const float* s = Wih + (size_t)j * IN_ + k0;
    half8 v;
#pragma unroll
    for (int e = 0; e < 8; ++e) v[e] = (_Float16)s[e];
    ((half8*)Adecpk)[id] = v;
}

// ---------------- FC weight pack ----------------
__global__ __launch_bounds__(256)
void pack_fcw(const float* __restrict__ fcW, _Float16* __restrict__ fcWpk)
{
    int id = blockIdx.x * 256 + threadIdx.x;      // < 32768
    int ot = id >> 11;
    int r  = id & 2047;
    int kc = r >> 6, l = r & 63;
    int o  = ot * 16 + (l & 15);
    int k0 = kc * 32 + ((l >> 4) << 3);
    const float* s = fcW + (size_t)o * HH + k0;
    half8 v;
#pragma unroll
    for (int e = 0; e < 8; ++e) v[e] = (_Float16)s[e];
    ((half8*)fcWpk)[id] = v;
}

// ---------------- x pack ----------------
__global__ __launch_bounds__(256)
void pack_x(const float* __restrict__ x, _Float16* __restrict__ Xpk)
{
    int id = blockIdx.x * 256 + threadIdx.x;  // < 1048576
    int l = id & 63, bt = (id >> 6) & 3, kc2 = (id >> 8) & 7, t = id >> 11;
    int b  = bt * 16 + (l & 15);
    int i0 = kc2 * 32 + ((l >> 4) << 3);
    const float* s = x + ((size_t)b * TT_ + t) * IN_ + i0;
    half8 v;
#pragma unroll
    for (int e = 0; e < 8; ++e) v[e] = (_Float16)s[e];
    ((half8*)Xpk)[id] = v;
}

__global__ __launch_bounds__(256)
void pack_bias(const float* __restrict__ bih, const float* __restrict__ bhh,
               float* __restrict__ biasc)
{
    int j = blockIdx.x * 256 + threadIdx.x;
    if (j < G4) biasc[j] = bih[j] + bhh[j];
}

// ---------------- persistent encoder v9: dataflow + partial re-issue poll ----------------
// grid 256 = (dq16 = bid>>2, grp = bid&3), block 256 (4 waves, 1 WG/CU).
// R13 structure; poll retries re-read ONLY still-poison vectors (non-poison
// words are final within a slot epoch) -> retry traffic drops ~5-10x,
// decongesting the LLC for the data trips themselves.
__global__ __launch_bounds__(256, 1)
void enc_persist(const _Float16* __restrict__ Apk,
                 const _Float16* __restrict__ Xpk,
                 _Float16* __restrict__ Hbuf,
                 const float* __restrict__ biasc,
                 float* __restrict__ cT,
                 float* __restrict__ hT)
{
    __shared__ __align__(16) _Float16 Ald[4 * 32 * 64 * 8];   // 128 KB
    __shared__ __align__(16) _Float16 Hst[32 * 64 * 8];       // 32 KB
    const int tid  = threadIdx.x;
    const int lane = tid & 63, t4 = tid >> 6;
    const int dq16 = blockIdx.x >> 2, grp = blockIdx.x & 3;
    const int q = lane >> 4, bl = lane & 15;
    const int d = dq16 * 16 + t4 * 4 + q;        // this thread's dim
    const int b = grp * 16 + bl;                 // this thread's batch
    const int jt = dq16 * 4 + t4;                // this wave's A-tile

    // ---- one-time: Whh A-frags -> LDS ----
    {
        const half8* src = (const half8*)Apk + ((size_t)jt * 40) * 64 + lane;
        half8* dst = (half8*)Ald + (size_t)t4 * 32 * 64 + lane;
#pragma unroll
        for (int kc = 0; kc < 32; ++kc) dst[kc * 64] = src[kc * 64];
    }
    // ---- one-time: Wih A-frags -> registers (8 frags) ----
    half8 xa[8];
    {
        const half8* src = (const half8*)Apk + ((size_t)jt * 40 + 32) * 64 + lane;
#pragma unroll
        for (int k = 0; k < 8; ++k) xa[k] = src[k * 64];
    }

    float bsum[4];
#pragma unroll
    for (int g = 0; g < 4; ++g) bsum[g] = biasc[g * HH + d];

    const half8* Ald8 = (const half8*)Ald + (size_t)t4 * 32 * 64 + lane;
    const half8* Hld8 = (const half8*)Hst + lane;
    uint4v* Hst16 = (uint4v*)Hst;

    // publish half-index within a slot (pair of dims d, d^1 packed as u32),
    // in fp16 units; slot stride = 65536 fp16
    const unsigned int pidx = ((unsigned)grp * 2048 + ((unsigned)d >> 5) * 64 +
                               (((unsigned)d >> 3) & 3) * 16 + bl) * 8 + (d & 7);

    float c_reg = 0.f, h_last = 0.f;
    __syncthreads();   // A-LDS ready

    for (int t = 0; t < TT_; ++t) {
        const int sIn  = (t - 1) & 63;
        const int sOut = t & 63;
        const int sPoi = (t + 8) & 63;

        f32x4 acc[4];
#pragma unroll
        for (int i = 0; i < 4; ++i) acc[i] = (f32x4){0.f, 0.f, 0.f, 0.f};

        // ---- X B-frags (plain cached; retire under the H poll wait) ----
        const half8* X8 = (const half8*)Xpk + ((size_t)t * 32 + grp) * 64 + lane;
        half8 xf[8];

        if (t > 0) {
            // ---- issue H loads for slot sIn (sc0sc1 -> LLC-coherent) ----
            // slot = 8192 uint4v (65536 fp16); group slice = 2048 uint4v
            const uint4v* Hsrc = (const uint4v*)Hbuf + (size_t)sIn * 8192 +
                                 (size_t)grp * 2048;
            uint4v tmp[8];
#pragma unroll
            for (int i = 0; i < 8; ++i) {
                asm volatile("global_load_dwordx4 %0, %1, off sc0 sc1"
                             : "=v"(tmp[i]) : "v"(Hsrc + i * 256 + tid));
            }
#pragma unroll
            for (int k = 0; k < 8; ++k) xf[k] = X8[k * 256];

            // ---- poll: re-read ONLY still-poison vectors (good words are
            // final for this slot epoch) ----
            for (;;) {
                asm volatile("s_waitcnt vmcnt(0)" ::: "memory");
                __builtin_amdgcn_sched_barrier(0);
                int bad[8];
                int any = 0;
#pragma unroll
                for (int i = 0; i < 8; ++i) {
                    bad[i] = (tmp[i].x == 0xFFFFFFFFu) | (tmp[i].y == 0xFFFFFFFFu) |
                             (tmp[i].z == 0xFFFFFFFFu) | (tmp[i].w == 0xFFFFFFFFu);
                    any |= bad[i];
                }
                if (__all(any == 0)) break;
#pragma unroll
                for (int i = 0; i < 8; ++i) {
                    if (bad[i]) {
                        asm volatile("global_load_dwordx4 %0, %1, off sc0 sc1"
                                     : "=v"(tmp[i]) : "v"(Hsrc + i * 256 + tid));
                    }
                }
                __builtin_amdgcn_s_sleep(1);
            }

            // ---- stage H to LDS ----
#pragma unroll
            for (int i = 0; i < 8; ++i) Hst16[i * 256 + tid] = tmp[i];
            __syncthreads();   // H-LDS ready

            // ---- 8 X-MFMAs + 32 H-MFMAs, 4 acc chains ----
#pragma unroll
            for (int k = 0; k < 8; ++k)
                acc[k & 3] = __builtin_amdgcn_mfma_f32_16x16x32_f16(xa[k], xf[k], acc[k & 3], 0, 0, 0);
#pragma unroll
            for (int kc = 0; kc < 32; ++kc) {
                half8 a  = Ald8[kc * 64];
                half8 bf = Hld8[kc * 64];
                acc[kc & 3] = __builtin_amdgcn_mfma_f32_16x16x32_f16(a, bf, acc[kc & 3], 0, 0, 0);
            }
        } else {
            // t = 0: h(-1) = 0 -> X contribution only
#pragma unroll
            for (int k = 0; k < 8; ++k) xf[k] = X8[k * 256];
#pragma unroll
            for (int k = 0; k < 8; ++k)
                acc[k & 3] = __builtin_amdgcn_mfma_f32_16x16x32_f16(xa[k], xf[k], acc[k & 3], 0, 0, 0);
        }

        // ---- gates fully in-register ----
        float pi = acc[0][0] + acc[1][0] + acc[2][0] + acc[3][0] + bsum[0];
        float pf = acc[0][1] + acc[1][1] + acc[2][1] + acc[3][1] + bsum[1];
        float pg = acc[0][2] + acc[1][2] + acc[2][2] + acc[3][2] + bsum[2];
        float po = acc[0][3] + acc[1][3] + acc[2][3] + acc[3][3] + bsum[3];
        float ig = sigmoidf_(pi), fg = sigmoidf_(pf);
        float gg = tanhf_(pg),    og = sigmoidf_(po);
        c_reg = fg * c_reg + ig * gg;
        float h = og * tanhf_(c_reg);
        h_last = h;

        // ---- publish h(t) to slot sOut + rolling re-poison of slot sPoi ----
        float hp = __shfl_xor(h, 16);    // partner q^1 -> dim d^1
        if (t < TT_ - 1 && !(q & 1)) {
            _Float16 h0 = (_Float16)h, h1 = (_Float16)hp;
            unsigned int pk = (unsigned int)__builtin_bit_cast(unsigned short, h0) |
                              ((unsigned int)__builtin_bit_cast(unsigned short, h1) << 16);
            unsigned int* po_ = (unsigned int*)(Hbuf + (size_t)sOut * 65536 + pidx);
            asm volatile("global_store_dword %0, %1, off sc0 sc1"
                         :: "v"(po_), "v"(pk) : "memory");
            unsigned int* pz = (unsigned int*)(Hbuf + (size_t)sPoi * 65536 + pidx);
            unsigned int poison = 0xFFFFFFFFu;
            asm volatile("global_store_dword %0, %1, off sc0 sc1"
                         :: "v"(pz), "v"(poison) : "memory");
        }
        // no drain, no flags: next step's poll vmcnt(0) retires these stores

        if (t < TT_ - 1) __syncthreads();   // protect Hst before next staging
    }

    // ---- final state for decoder ----
    cT[d * 64 + b] = c_reg;
    hT[d * 64 + b] = h_last;
}

// ---------------- hdecg = h_final @ dec_Whh^T + biases (gate-major out) ----------------
__global__ __launch_bounds__(256)
void hdec_kernel(const float* __restrict__ hT, const float* __restrict__ Whh,
                 const float* __restrict__ bih, const float* __restrict__ bhh,
                 float* __restrict__ hdecg)
{
    __shared__ float hb[1024];
    const int tid = threadIdx.x;
    const int b  = blockIdx.x >> 2;
    const int j0 = (blockIdx.x & 3) * 1024;
#pragma unroll
    for (int u = 0; u < 4; ++u) {
        int k = u * 256 + tid;
        hb[k] = hT[k * 64 + b];
    }
    __syncthreads();
#pragma unroll
    for (int rr = 0; rr < 4; ++rr) {
        int j = j0 + rr * 256 + tid;
        const float* wr = Whh + (size_t)j * HH;
        float a = bih[j] + bhh[j];
        for (int k = 0; k < 1024; k += 4) {
            float4 wv = *(const float4*)(wr + k);
            float4 hv = *(const float4*)&hb[k];
            a += hv.x * wv.x + hv.y * wv.y + hv.z * wv.z + hv.w * wv.w;
        }
        hdecg[((size_t)(j >> 10) * 1024 + (j & 1023)) * 64 + b] = a;
    }
}

// ---------------- MFMA decoder (unchanged) ----------------
__global__ __launch_bounds__(256)
void dec_mfma(const _Float16* __restrict__ Adecpk,
              const _Float16* __restrict__ fcWpk,
              const _Float16* __restrict__ Xpk,
              const float* __restrict__ hdecg,
              const float* __restrict__ cT,
              const float* __restrict__ fcb,
              float* __restrict__ out)
{
    __shared__ __align__(16) _Float16 Hn[32 * 64 * 8];   // 32 KB
    __shared__ __align__(16) float outl[16][260];
    const int tid = threadIdx.x;
    const int lane = tid & 63, w = tid >> 6;
    const int t = blockIdx.x >> 2, bq4 = blockIdx.x & 3;
    const int q = lane >> 4, bl = lane & 15;
    const int bg = bq4 * 16 + bl;

    const half8* X8 = (const half8*)Xpk + ((size_t)t * 32 + bq4) * 64 + lane;
    half8 xf[8];
#pragma unroll
    for (int kc2 = 0; kc2 < 8; ++kc2) xf[kc2] = X8[kc2 * 256];

    const half8* AD = (const half8*)Adecpk + lane;
    for (int dqi = 0; dqi < 32; ++dqi) {
        int dq = w * 32 + dqi;
#pragma unroll
        for (int t2 = 0; t2 < 2; ++t2) {
            f32x4 acc = {0.f, 0.f, 0.f, 0.f};
#pragma unroll
            for (int kc2 = 0; kc2 < 8; ++kc2) {
                half8 a = AD[((size_t)(dq * 2 + t2) * 8 + kc2) * 64];
                acc = __builtin_amdgcn_mfma_f32_16x16x32_f16(a, xf[kc2], acc, 0, 0, 0);
            }
            int d = dq * 8 + t2 * 4 + q;
            float cv = cT[d * 64 + bg];
            float pi = acc[0] + hdecg[(size_t)(0 * HH + d) * 64 + bg];
            float pf = acc[1] + hdecg[(size_t)(1 * HH + d) * 64 + bg];
            float pg = acc[2] + hdecg[(size_t)(2 * HH + d) * 64 + bg];
            float po = acc[3] + hdecg[(size_t)(3 * HH + d) * 64 + bg];
            float ig = sigmoidf_(pi), fg = sigmoidf_(pf);
            float gg = tanhf_(pg),    og = sigmoidf_(po);
            float cn = fg * cv + ig * gg;
            float h = og * tanhf_(cn);
            Hn[((d >> 5) * 64 + ((d >> 3) & 3) * 16 + bl) * 8 + (d & 7)] = (_Float16)h;
        }
    }
    __syncthreads();

    const half8* Hn8 = (const half8*)Hn + lane;
    const half8* FW = (const half8*)fcWpk + lane;
#pragma unroll
    for (int oti = 0; oti < 4; ++oti) {
        int ot = w * 4 + oti;
        f32x4 acc = {0.f, 0.f, 0.f, 0.f};
        for (int kc = 0; kc < 32; ++kc) {
            half8 a  = FW[((size_t)ot * 32 + kc) * 64];
            half8 bf = Hn8[kc * 64];
            acc = __builtin_amdgcn_mfma_f32_16x16x32_f16(a, bf, acc, 0, 0, 0);
        }
#pragma unroll
        for (int r = 0; r < 4; ++r) {
            int o = ot * 16 + q * 4 + r;
            outl[bl][o] = acc[r] + fcb[o];
        }
    }
    __syncthreads();

#pragma unroll
    for (int i = 0; i < 16; ++i) {
        int b = bq4 * 16 + i;
        out[((size_t)b * TT_ + t) * OO + tid] = outl[i][tid];
    }
}

extern "C" void kernel_launch(void* const* d_in, const int* in_sizes, int n_in,
                              void* d_out, int out_size, void* d_ws, size_t ws_size,
                              hipStream_t stream) {
    const float* x    = (const float*)d_in[0];
    const float* eWih = (const float*)d_in[1];
    const float* eWhh = (const float*)d_in[2];
    const float* ebih = (const float*)d_in[3];
    const float* ebhh = (const float*)d_in[4];
    const float* dWih = (const float*)d_in[5];
    const float* dWhh = (const float*)d_in[6];
    const float* dbih = (const float*)d_in[7];
    const float* dbhh = (const float*)d_in[8];
    const float* fcW  = (const float*)d_in[9];
    const float* fcb  = (const float*)d_in[10];

    // ws layout (f32 words): hT 65536 | cT 65536 | hdecg 262144 | biasc 4096 |
    // then fp16: Hbuf 64 slots x 65536 = 4194304 | Apk 5242880 | Xpk 8388608 |
    // Adecpk 1048576 | fcWpk 262144   (~40 MB total)
    float* ws    = (float*)d_ws;
    float* hT    = ws;
    float* cT    = ws + 65536;
    float* hdecg = ws + 131072;
    float* biasc = ws + 393216;
    _Float16* fp  = (_Float16*)(ws + 397568);
    _Float16* Hbuf = fp;
    _Float16* Apk  = fp + 4194304;
    _Float16* Xpk  = Apk + 5242880;
    _Float16* Adecpk = Xpk + 8388608;
    _Float16* fcWpk  = Adecpk + 1048576;

    pack_a2<<<dim3(2560), dim3(256), 0, stream>>>(eWhh, eWih, Apk);
    pack_x<<<dim3(4096), dim3(256), 0, stream>>>(x, Xpk);
    pack_bias<<<dim3(16), dim3(256), 0, stream>>>(ebih, ebhh, biasc);
    pack_adec<<<dim3(512), dim3(256), 0, stream>>>(dWih, Adecpk);
    pack_fcw<<<dim3(128), dim3(256), 0, stream>>>(fcW, fcWpk);
    // poison all 64 h slots (0xFF bytes -> u32 0xFFFFFFFF = fp16 NaN pair)
    hipMemsetAsync(Hbuf, 0xFF, (size_t)4194304 * sizeof(_Float16), stream);

    enc_persist<<<dim3(256), dim3(256), 0, stream>>>(
        Apk, Xpk, Hbuf, biasc, cT, hT);

    hdec_kernel<<<dim3(256), dim3(256), 0, stream>>>(hT, dWhh, dbih, dbhh, hdecg);
    dec_mfma<<<dim3(2048), dim3(256), 0, stream>>>(Adecpk, fcWpk, Xpk, hdecg, cT,
                                                   fcb, (float*)d_out);
}

// Round 15
// 1615.328 us; speedup vs baseline: 3.5641x; 1.4485x over previous
//
#include <hip/hip_runtime.h>
#include <hip/hip_bf16.h>

#define BB 64
#define TT_ 512
#define IN_ 256
#define HH 1024
#define G4 4096
#define OO 256

typedef _Float16 half8 __attribute__((ext_vector_type(8)));
typedef float f32x4 __attribute__((ext_vector_type(4)));
typedef unsigned int uint4v __attribute__((ext_vector_type(4)));

__device__ __forceinline__ float sigmoidf_(float v) {
    return 1.f / (1.f + __expf(-v));
}
__device__ __forceinline__ float tanhf_(float v) {
    float vc = fminf(fmaxf(v, -15.f), 15.f);
    float e = __expf(2.f * vc);
    return (e - 1.f) / (e + 1.f);
}

// ---------------- encoder weight pack ----------------
// Apk[jt(256)][kc(40)][lane(64)][e(8)] fp16; jt = global 4-dim tile (= d>>2).
// Tile rows rD = ddl*4 + g -> MFMA acc[r] of lane (q=l>>4) holds gate r of
// dim jt*4 + q. kc 0..31 = Whh K, kc 32..39 = Wih K.
__global__ __launch_bounds__(256)
void pack_a2(const float* __restrict__ Whh, const float* __restrict__ Wih,
             _Float16* __restrict__ Apk)
{
    int id = blockIdx.x * 256 + threadIdx.x;      // 16B-unit id < 655360
    int dq  = id / 5120;
    int r1  = id - dq * 5120;
    int t2  = r1 / 2560;
    int r2  = r1 - t2 * 2560;
    int kc  = r2 >> 6, l = r2 & 63;
    int rD  = l & 15;
    int g   = rD & 3, ddl = rD >> 2;
    int d   = dq * 8 + t2 * 4 + ddl;
    int j   = g * HH + d;
    int k0  = kc * 32 + ((l >> 4) << 3);
    half8 v;
    if (kc < 32) {
        const float* s = Whh + (size_t)j * HH + k0;
#pragma unroll
        for (int e = 0; e < 8; ++e) v[e] = (_Float16)s[e];
    } else {
        const float* s = Wih + (size_t)j * IN_ + (k0 - 1024);
#pragma unroll
        for (int e = 0; e < 8; ++e) v[e] = (_Float16)s[e];
    }
    ((half8*)Apk)[id] = v;
}

// ---------------- decoder weight pack ----------------
__global__ __launch_bounds__(256)
void pack_adec(const float* __restrict__ Wih, _Float16* __restrict__ Adecpk)
{
    int id = blockIdx.x * 256 + threadIdx.x;      // < 131072
    int dq = id >> 10;
    int r1 = id & 1023;
    int t2 = r1 >> 9;
    int r2 = r1 & 511;
    int kc2 = r2 >> 6, l = r2 & 63;
    int rD = l & 15, g = rD & 3, ddl = rD >> 2;
    int d  = dq * 8 + t2 * 4 + ddl;
    int j  = g * HH + d;
    int k0 = kc2 * 32 + ((l >> 4) << 3);
    const float* s = Wih + (size_t)j * IN_ + k0;
    half8 v;
#pragma unroll
    for (int e = 0; e < 8; ++e) v[e] = (_Float16)s[e];
    ((half8*)Adecpk)[id] = v;
}

// ---------------- FC weight pack ----------------
__global__ __launch_bounds__(256)
void pack_fcw(const float* __restrict__ fcW, _Float16* __restrict__ fcWpk)
{
    int id = blockIdx.x * 256 + threadIdx.x;      // < 32768
    int ot = id >> 11;
    int r  = id & 2047;
    int kc = r >> 6, l = r & 63;
    int o  = ot * 16 + (l & 15);
    int k0 = kc * 32 + ((l >> 4) << 3);
    const float* s = fcW + (size_t)o * HH + k0;
    half8 v;
#pragma unroll
    for (int e = 0; e < 8; ++e) v[e] = (_Float16)s[e];
    ((half8*)fcWpk)[id] = v;
}

// ---------------- x pack ----------------
__global__ __launch_bounds__(256)
void pack_x(const float* __restrict__ x, _Float16* __restrict__ Xpk)
{
    int id = blockIdx.x * 256 + threadIdx.x;  // < 1048576
    int l = id & 63, bt = (id >> 6) & 3, kc2 = (id >> 8) & 7, t = id >> 11;
    int b  = bt * 16 + (l & 15);
    int i0 = kc2 * 32 + ((l >> 4) << 3);
    const float* s = x + ((size_t)b * TT_ + t) * IN_ + i0;
    half8 v;
#pragma unroll
    for (int e = 0; e < 8; ++e) v[e] = (_Float16)s[e];
    ((half8*)Xpk)[id] = v;
}

__global__ __launch_bounds__(256)
void pack_bias(const float* __restrict__ bih, const float* __restrict__ bhh,
               float* __restrict__ biasc)
{
    int j = blockIdx.x * 256 + threadIdx.x;
    if (j < G4) biasc[j] = bih[j] + bhh[j];
}

// ---------------- persistent encoder v10: dataflow + register-resident H ----------------
// grid 256 = (dq16 = bid>>2, grp = bid&3), block 256 (4 waves, 1 WG/CU).
// K-split by residency: tmp[i] (H load, i*256+tid) IS the B-frag for
// kc = i*4 + w. Wave w computes partials for ALL 4 tiles over its 8 resident
// kc (A from LDS), X-MFMAs for its own tile under the H flight; partials
// reduced via 16 KB LDS exchange. No H staging, no H B-frag LDS reads.
// Poison-tagged h slots as R13/R14 (partial re-issue poll).
__global__ __launch_bounds__(256, 1)
void enc_persist(const _Float16* __restrict__ Apk,
                 const _Float16* __restrict__ Xpk,
                 _Float16* __restrict__ Hbuf,
                 const float* __restrict__ biasc,
                 float* __restrict__ cT,
                 float* __restrict__ hT)
{
    __shared__ __align__(16) _Float16 Ald[4 * 32 * 64 * 8];   // 128 KB
    __shared__ __align__(16) f32x4 pp[16 * 64];               // 16 KB
    const int tid  = threadIdx.x;
    const int lane = tid & 63, w = tid >> 6;
    const int dq16 = blockIdx.x >> 2, grp = blockIdx.x & 3;
    const int q = lane >> 4, bl = lane & 15;
    const int d = dq16 * 16 + w * 4 + q;         // this thread's dim (own tile)
    const int b = grp * 16 + bl;                 // this thread's batch

    // ---- one-time: each wave loads its tile's 32 Whh A-frags -> LDS ----
    {
        const half8* src = (const half8*)Apk + ((size_t)(dq16 * 4 + w) * 40) * 64 + lane;
        half8* dst = (half8*)Ald + (size_t)w * 2048 + lane;
#pragma unroll
        for (int kc = 0; kc < 32; ++kc) dst[kc * 64] = src[kc * 64];
    }
    // ---- one-time: own tile's Wih A-frags -> registers (8 frags) ----
    half8 xa[8];
    {
        const half8* src = (const half8*)Apk + ((size_t)(dq16 * 4 + w) * 40 + 32) * 64 + lane;
#pragma unroll
        for (int k = 0; k < 8; ++k) xa[k] = src[k * 64];
    }

    float bsum[4];
#pragma unroll
    for (int g = 0; g < 4; ++g) bsum[g] = biasc[g * HH + d];

    const half8* Ald8 = (const half8*)Ald + lane;   // + jl*2048 + kc*64

    // publish half-index within a slot (pair of dims d, d^1 packed as u32),
    // in fp16 units; slot stride = 65536 fp16
    const unsigned int pidx = ((unsigned)grp * 2048 + ((unsigned)d >> 5) * 64 +
                               (((unsigned)d >> 3) & 3) * 16 + bl) * 8 + (d & 7);

    float c_reg = 0.f, h_last = 0.f;
    __syncthreads();   // A-LDS ready

    for (int t = 0; t < TT_; ++t) {
        const int sIn  = (t - 1) & 63;
        const int sOut = t & 63;
        const int sPoi = (t + 8) & 63;

        // ---- issue xf loads FIRST (plain), then H (sc0sc1) ----
        const uint4v* Xsrc = (const uint4v*)Xpk + ((size_t)t * 32 + grp) * 64 + lane;
        uint4v xft[8];
#pragma unroll
        for (int k = 0; k < 8; ++k) {
            asm volatile("global_load_dwordx4 %0, %1, off"
                         : "=v"(xft[k]) : "v"(Xsrc + k * 256));
        }
        uint4v tmp[8];
        const uint4v* Hsrc = (const uint4v*)Hbuf + (size_t)sIn * 8192 +
                             (size_t)grp * 2048;
        if (t > 0) {
#pragma unroll
            for (int i = 0; i < 8; ++i) {
                asm volatile("global_load_dwordx4 %0, %1, off sc0 sc1"
                             : "=v"(tmp[i]) : "v"(Hsrc + i * 256 + tid));
            }
            // wait xf (oldest 8 + prev-iter stores); H stays in flight
            asm volatile("s_waitcnt vmcnt(8)" ::: "memory");
        } else {
            asm volatile("s_waitcnt vmcnt(0)" ::: "memory");
        }
        __builtin_amdgcn_sched_barrier(0);

        // ---- X-MFMAs (own tile) under the H shadow ----
        f32x4 accX = {0.f, 0.f, 0.f, 0.f};
#pragma unroll
        for (int k = 0; k < 8; ++k) {
            half8 bf = __builtin_bit_cast(half8, xft[k]);
            accX = __builtin_amdgcn_mfma_f32_16x16x32_f16(xa[k], bf, accX, 0, 0, 0);
        }

        // ---- H partials for all 4 tiles over this wave's 8 resident kc ----
        f32x4 accT[4];
#pragma unroll
        for (int jl = 0; jl < 4; ++jl) accT[jl] = (f32x4){0.f, 0.f, 0.f, 0.f};

        if (t > 0) {
            // poll: re-read ONLY still-poison vectors (good words are final)
            for (;;) {
                asm volatile("s_waitcnt vmcnt(0)" ::: "memory");
                __builtin_amdgcn_sched_barrier(0);
                int bad[8];
                int any = 0;
#pragma unroll
                for (int i = 0; i < 8; ++i) {
                    bad[i] = (tmp[i].x == 0xFFFFFFFFu) | (tmp[i].y == 0xFFFFFFFFu) |
                             (tmp[i].z == 0xFFFFFFFFu) | (tmp[i].w == 0xFFFFFFFFu);
                    any |= bad[i];
                }
                if (__all(any == 0)) break;
#pragma unroll
                for (int i = 0; i < 8; ++i) {
                    if (bad[i]) {
                        asm volatile("global_load_dwordx4 %0, %1, off sc0 sc1"
                                     : "=v"(tmp[i]) : "v"(Hsrc + i * 256 + tid));
                    }
                }
                __builtin_amdgcn_s_sleep(1);
            }

            // tmp[i] = B-frag(kc = i*4 + w); A-frags for all 4 tiles from LDS
#pragma unroll
            for (int i = 0; i < 8; ++i) {
                const int kc = i * 4 + w;
                half8 bf = __builtin_bit_cast(half8, tmp[i]);
#pragma unroll
                for (int jl = 0; jl < 4; ++jl) {
                    half8 a = Ald8[jl * 2048 + kc * 64];
                    accT[jl] = __builtin_amdgcn_mfma_f32_16x16x32_f16(a, bf, accT[jl], 0, 0, 0);
                }
            }
        }

        // ---- cross-wave K-reduction: pp[w][jl] = accT[jl]; owner jl sums ----
#pragma unroll
        for (int jl = 0; jl < 4; ++jl)
            pp[(w * 4 + jl) * 64 + lane] = accT[jl];
        __syncthreads();   // partials ready

        f32x4 s = accX;
#pragma unroll
        for (int w2 = 0; w2 < 4; ++w2)
            s += pp[(w2 * 4 + w) * 64 + lane];

        // ---- gates fully in-register ----
        float pi = s[0] + bsum[0];
        float pf = s[1] + bsum[1];
        float pg = s[2] + bsum[2];
        float po = s[3] + bsum[3];
        float ig = sigmoidf_(pi), fg = sigmoidf_(pf);
        float gg = tanhf_(pg),    og = sigmoidf_(po);
        c_reg = fg * c_reg + ig * gg;
        float h = og * tanhf_(c_reg);
        h_last = h;

        // ---- publish h(t) to slot sOut + rolling re-poison of slot sPoi ----
        float hp = __shfl_xor(h, 16);    // partner q^1 -> dim d^1
        if (t < TT_ - 1 && !(q & 1)) {
            _Float16 h0 = (_Float16)h, h1 = (_Float16)hp;
            unsigned int pk = (unsigned int)__builtin_bit_cast(unsigned short, h0) |
                              ((unsigned int)__builtin_bit_cast(unsigned short, h1) << 16);
            unsigned int* po_ = (unsigned int*)(Hbuf + (size_t)sOut * 65536 + pidx);
            asm volatile("global_store_dword %0, %1, off sc0 sc1"
                         :: "v"(po_), "v"(pk) : "memory");
            unsigned int* pz = (unsigned int*)(Hbuf + (size_t)sPoi * 65536 + pidx);
            unsigned int poison = 0xFFFFFFFFu;
            asm volatile("global_store_dword %0, %1, off sc0 sc1"
                         :: "v"(pz), "v"(poison) : "memory");
        }
        // stores drained by next step's poll vmcnt; no flags, no drains here

        if (t < TT_ - 1) __syncthreads();   // protect pp before next exchange
    }

    // ---- final state for decoder ----
    cT[d * 64 + b] = c_reg;
    hT[d * 64 + b] = h_last;
}

// ---------------- hdecg = h_final @ dec_Whh^T + biases (gate-major out) ----------------
__global__ __launch_bounds__(256)
void hdec_kernel(const float* __restrict__ hT, const float* __restrict__ Whh,
                 const float* __restrict__ bih, const float* __restrict__ bhh,
                 float* __restrict__ hdecg)
{
    __shared__ float hb[1024];
    const int tid = threadIdx.x;
    const int b  = blockIdx.x >> 2;
    const int j0 = (blockIdx.x & 3) * 1024;
#pragma unroll
    for (int u = 0; u < 4; ++u) {
        int k = u * 256 + tid;
        hb[k] = hT[k * 64 + b];
    }
    __syncthreads();
#pragma unroll
    for (int rr = 0; rr < 4; ++rr) {
        int j = j0 + rr * 256 + tid;
        const float* wr = Whh + (size_t)j * HH;
        float a = bih[j] + bhh[j];
        for (int k = 0; k < 1024; k += 4) {
            float4 wv = *(const float4*)(wr + k);
            float4 hv = *(const float4*)&hb[k];
            a += hv.x * wv.x + hv.y * wv.y + hv.z * wv.z + hv.w * wv.w;
        }
        hdecg[((size_t)(j >> 10) * 1024 + (j & 1023)) * 64 + b] = a;
    }
}

// ---------------- MFMA decoder (unchanged) ----------------
__global__ __launch_bounds__(256)
void dec_mfma(const _Float16* __restrict__ Adecpk,
              const _Float16* __restrict__ fcWpk,
              const _Float16* __restrict__ Xpk,
              const float* __restrict__ hdecg,
              const float* __restrict__ cT,
              const float* __restrict__ fcb,
              float* __restrict__ out)
{
    __shared__ __align__(16) _Float16 Hn[32 * 64 * 8];   // 32 KB
    __shared__ __align__(16) float outl[16][260];
    const int tid = threadIdx.x;
    const int lane = tid & 63, w = tid >> 6;
    const int t = blockIdx.x >> 2, bq4 = blockIdx.x & 3;
    const int q = lane >> 4, bl = lane & 15;
    const int bg = bq4 * 16 + bl;

    const half8* X8 = (const half8*)Xpk + ((size_t)t * 32 + bq4) * 64 + lane;
    half8 xf[8];
#pragma unroll
    for (int kc2 = 0; kc2 < 8; ++kc2) xf[kc2] = X8[kc2 * 256];

    const half8* AD = (const half8*)Adecpk + lane;
    for (int dqi = 0; dqi < 32; ++dqi) {
        int dq = w * 32 + dqi;
#pragma unroll
        for (int t2 = 0; t2 < 2; ++t2) {
            f32x4 acc = {0.f, 0.f, 0.f, 0.f};
#pragma unroll
            for (int kc2 = 0; kc2 < 8; ++kc2) {
                half8 a = AD[((size_t)(dq * 2 + t2) * 8 + kc2) * 64];
                acc = __builtin_amdgcn_mfma_f32_16x16x32_f16(a, xf[kc2], acc, 0, 0, 0);
            }
            int d = dq * 8 + t2 * 4 + q;
            float cv = cT[d * 64 + bg];
            float pi = acc[0] + hdecg[(size_t)(0 * HH + d) * 64 + bg];
            float pf = acc[1] + hdecg[(size_t)(1 * HH + d) * 64 + bg];
            float pg = acc[2] + hdecg[(size_t)(2 * HH + d) * 64 + bg];
            float po = acc[3] + hdecg[(size_t)(3 * HH + d) * 64 + bg];
            float ig = sigmoidf_(pi), fg = sigmoidf_(pf);
            float gg = tanhf_(pg),    og = sigmoidf_(po);
            float cn = fg * cv + ig * gg;
            float h = og * tanhf_(cn);
            Hn[((d >> 5) * 64 + ((d >> 3) & 3) * 16 + bl) * 8 + (d & 7)] = (_Float16)h;
        }
    }
    __syncthreads();

    const half8* Hn8 = (const half8*)Hn + lane;
    const half8* FW = (const half8*)fcWpk + lane;
#pragma unroll
    for (int oti = 0; oti < 4; ++oti) {
        int ot = w * 4 + oti;
        f32x4 acc = {0.f, 0.f, 0.f, 0.f};
        for (int kc = 0; kc < 32; ++kc) {
            half8 a  = FW[((size_t)ot * 32 + kc) * 64];
            half8 bf = Hn8[kc * 64];
            acc = __builtin_amdgcn_mfma_f32_16x16x32_f16(a, bf, acc, 0, 0, 0);
        }
#pragma unroll
        for (int r = 0; r < 4; ++r) {
            int o = ot * 16 + q * 4 + r;
            outl[bl][o] = acc[r] + fcb[o];
        }
    }
    __syncthreads();

#pragma unroll
    for (int i = 0; i < 16; ++i) {
        int b = bq4 * 16 + i;
        out[((size_t)b * TT_ + t) * OO + tid] = outl[i][tid];
    }
}

extern "C" void kernel_launch(void* const* d_in, const int* in_sizes, int n_in,
                              void* d_out, int out_size, void* d_ws, size_t ws_size,
                              hipStream_t stream) {
    const float* x    = (const float*)d_in[0];
    const float* eWih = (const float*)d_in[1];
    const float* eWhh = (const float*)d_in[2];
    const float* ebih = (const float*)d_in[3];
    const float* ebhh = (const float*)d_in[4];
    const float* dWih = (const float*)d_in[5];
    const float* dWhh = (const float*)d_in[6];
    const float* dbih = (const float*)d_in[7];
    const float* dbhh = (const float*)d_in[8];
    const float* fcW  = (const float*)d_in[9];
    const float* fcb  = (const float*)d_in[10];

    // ws layout (f32 words): hT 65536 | cT 65536 | hdecg 262144 | biasc 4096 |
    // then fp16: Hbuf 64 slots x 65536 = 4194304 | Apk 5242880 | Xpk 8388608 |
    // Adecpk 1048576 | fcWpk 262144   (~40 MB total)
    float* ws    = (float*)d_ws;
    float* hT    = ws;
    float* cT    = ws + 65536;
    float* hdecg = ws + 131072;
    float* biasc = ws + 393216;
    _Float16* fp  = (_Float16*)(ws + 397568);
    _Float16* Hbuf = fp;
    _Float16* Apk  = fp + 4194304;
    _Float16* Xpk  = Apk + 5242880;
    _Float16* Adecpk = Xpk + 8388608;
    _Float16* fcWpk  = Adecpk + 1048576;

    pack_a2<<<dim3(2560), dim3(256), 0, stream>>>(eWhh, eWih, Apk);
    pack_x<<<dim3(4096), dim3(256), 0, stream>>>(x, Xpk);
    pack_bias<<<dim3(16), dim3(256), 0, stream>>>(ebih, ebhh, biasc);
    pack_adec<<<dim3(512), dim3(256), 0, stream>>>(dWih, Adecpk);
    pack_fcw<<<dim3(128), dim3(256), 0, stream>>>(fcW, fcWpk);
    // poison all 64 h slots (0xFF bytes -> u32 0xFFFFFFFF = fp16 NaN pair)
    hipMemsetAsync(Hbuf, 0xFF, (size_t)4194304 * sizeof(_Float16), stream);

    enc_persist<<<dim3(256), dim3(256), 0, stream>>>(
        Apk, Xpk, Hbuf, biasc, cT, hT);

    hdec_kernel<<<dim3(256), dim3(256), 0, stream>>>(hT, dWhh, dbih, dbhh, hdecg);
    dec_mfma<<<dim3(2048), dim3(256), 0, stream>>>(Adecpk, fcWpk, Xpk, hdecg, cT,
                                                   fcb, (float*)d_out);
}

// Round 17
// 1493.465 us; speedup vs baseline: 3.8549x; 1.0816x over previous
//
#include <hip/hip_runtime.h>
#include <hip/hip_bf16.h>

#define BB 64
#define TT_ 512
#define IN_ 256
#define HH 1024
#define G4 4096
#define OO 256

typedef _Float16 half8 __attribute__((ext_vector_type(8)));
typedef float f32x4 __attribute__((ext_vector_type(4)));
typedef unsigned int uint4v __attribute__((ext_vector_type(4)));

__device__ __forceinline__ float sigmoidf_(float v) {
    return 1.f / (1.f + __expf(-v));
}
__device__ __forceinline__ float tanhf_(float v) {
    float vc = fminf(fmaxf(v, -15.f), 15.f);
    float e = __expf(2.f * vc);
    return (e - 1.f) / (e + 1.f);
}

// ---------------- encoder weight pack ----------------
// Apk[jt(256)][kc(40)][lane(64)][e(8)] fp16; jt = global 4-dim tile (= d>>2).
// Tile rows rD = ddl*4 + g -> MFMA acc[r] of lane (q=l>>4) holds gate r of
// dim jt*4 + q. kc 0..31 = Whh K, kc 32..39 = Wih K.
__global__ __launch_bounds__(256)
void pack_a2(const float* __restrict__ Whh, const float* __restrict__ Wih,
             _Float16* __restrict__ Apk)
{
    int id = blockIdx.x * 256 + threadIdx.x;      // 16B-unit id < 655360
    int dq  = id / 5120;
    int r1  = id - dq * 5120;
    int t2  = r1 / 2560;
    int r2  = r1 - t2 * 2560;
    int kc  = r2 >> 6, l = r2 & 63;
    int rD  = l & 15;
    int g   = rD & 3, ddl = rD >> 2;
    int d   = dq * 8 + t2 * 4 + ddl;
    int j   = g * HH + d;
    int k0  = kc * 32 + ((l >> 4) << 3);
    half8 v;
    if (kc < 32) {
        const float* s = Whh + (size_t)j * HH + k0;
#pragma unroll
        for (int e = 0; e < 8; ++e) v[e] = (_Float16)s[e];
    } else {
        const float* s = Wih + (size_t)j * IN_ + (k0 - 1024);
#pragma unroll
        for (int e = 0; e < 8; ++e) v[e] = (_Float16)s[e];
    }
    ((half8*)Apk)[id] = v;
}

// ---------------- dec Whh pack (gate-interleaved, K=1024) ----------------
// Ahhpk[jt(256)][kc(32)][lane(64)][e(8)]
__global__ __launch_bounds__(256)
void pack_ahh(const float* __restrict__ Whh, _Float16* __restrict__ Ahhpk)
{
    int id = blockIdx.x * 256 + threadIdx.x;      // < 524288
    int jt = id >> 11;
    int r  = id & 2047;
    int kc = r >> 6, l = r & 63;
    int rD = l & 15, g = rD & 3, ddl = rD >> 2;
    int d  = jt * 4 + ddl;
    int j  = g * HH + d;
    int k0 = kc * 32 + ((l >> 4) << 3);
    const float* s = Whh + (size_t)j * HH + k0;
    half8 v;
#pragma unroll
    for (int e = 0; e < 8; ++e) v[e] = (_Float16)s[e];
    ((half8*)Ahhpk)[id] = v;
}

// ---------------- decoder weight pack ----------------
__global__ __launch_bounds__(256)
void pack_adec(const float* __restrict__ Wih, _Float16* __restrict__ Adecpk)
{
    int id = blockIdx.x * 256 + threadIdx.x;      // < 131072
    int dq = id >> 10;
    int r1 = id & 1023;
    int t2 = r1 >> 9;
    int r2 = r1 & 511;
    int kc2 = r2 >> 6, l = r2 & 63;
    int rD = l & 15, g = rD & 3, ddl = rD >> 2;
    int d  = dq * 8 + t2 * 4 + ddl;
    int j  = g * HH + d;
    int k0 = kc2 * 32 + ((l >> 4) << 3);
    const float* s = Wih + (size_t)j * IN_ + k0;
    half8 v;
#pragma unroll
    for (int e = 0; e < 8; ++e) v[e] = (_Float16)s[e];
    ((half8*)Adecpk)[id] = v;
}

// ---------------- FC weight pack ----------------
__global__ __launch_bounds__(256)
void pack_fcw(const float* __restrict__ fcW, _Float16* __restrict__ fcWpk)
{
    int id = blockIdx.x * 256 + threadIdx.x;      // < 32768
    int ot = id >> 11;
    int r  = id & 2047;
    int kc = r >> 6, l = r & 63;
    int o  = ot * 16 + (l & 15);
    int k0 = kc * 32 + ((l >> 4) << 3);
    const float* s = fcW + (size_t)o * HH + k0;
    half8 v;
#pragma unroll
    for (int e = 0; e < 8; ++e) v[e] = (_Float16)s[e];
    ((half8*)fcWpk)[id] = v;
}

// ---------------- x pack ----------------
__global__ __launch_bounds__(256)
void pack_x(const float* __restrict__ x, _Float16* __restrict__ Xpk)
{
    int id = blockIdx.x * 256 + threadIdx.x;  // < 1048576
    int l = id & 63, bt = (id >> 6) & 3, kc2 = (id >> 8) & 7, t = id >> 11;
    int b  = bt * 16 + (l & 15);
    int i0 = kc2 * 32 + ((l >> 4) << 3);
    const float* s = x + ((size_t)b * TT_ + t) * IN_ + i0;
    half8 v;
#pragma unroll
    for (int e = 0; e < 8; ++e) v[e] = (_Float16)s[e];
    ((half8*)Xpk)[id] = v;
}

__global__ __launch_bounds__(256)
void pack_bias(const float* __restrict__ bih, const float* __restrict__ bhh,
               float* __restrict__ biasc)
{
    int j = blockIdx.x * 256 + threadIdx.x;
    if (j < G4) biasc[j] = bih[j] + bhh[j];
}

// ---------------- persistent encoder v12: R15 poll (proven) + publish-every-step ----------------
// grid 256 = (dq16 = bid>>2, grp = bid&3), block 256 (4 waves, 1 WG/CU).
// Register-resident H (tmp[i] IS B-frag kc=i*4+w); wave w computes partials
// for all 4 tiles over its 8 resident kc; 16KB LDS exchange. Poll = R15's
// partial-re-issue form (consume AFTER poll completes — R16's in-loop consume
// livelocked via spilled asm-output regs). Publish EVERY step: slot
// (TT_-1)&63 holds final h in B-frag layout for hdec_mfma.
__global__ __launch_bounds__(256, 1)
void enc_persist(const _Float16* __restrict__ Apk,
                 const _Float16* __restrict__ Xpk,
                 _Float16* __restrict__ Hbuf,
                 const float* __restrict__ biasc,
                 float* __restrict__ cT)
{
    __shared__ __align__(16) _Float16 Ald[4 * 32 * 64 * 8];   // 128 KB
    __shared__ __align__(16) f32x4 pp[16 * 64];               // 16 KB
    const int tid  = threadIdx.x;
    const int lane = tid & 63, w = tid >> 6;
    const int dq16 = blockIdx.x >> 2, grp = blockIdx.x & 3;
    const int q = lane >> 4, bl = lane & 15;
    const int d = dq16 * 16 + w * 4 + q;         // this thread's dim (own tile)
    const int b = grp * 16 + bl;                 // this thread's batch

    // ---- one-time: each wave loads its tile's 32 Whh A-frags -> LDS ----
    {
        const half8* src = (const half8*)Apk + ((size_t)(dq16 * 4 + w) * 40) * 64 + lane;
        half8* dst = (half8*)Ald + (size_t)w * 2048 + lane;
#pragma unroll
        for (int kc = 0; kc < 32; ++kc) dst[kc * 64] = src[kc * 64];
    }
    // ---- one-time: own tile's Wih A-frags -> registers (8 frags) ----
    half8 xa[8];
    {
        const half8* src = (const half8*)Apk + ((size_t)(dq16 * 4 + w) * 40 + 32) * 64 + lane;
#pragma unroll
        for (int k = 0; k < 8; ++k) xa[k] = src[k * 64];
    }

    float bsum[4];
#pragma unroll
    for (int g = 0; g < 4; ++g) bsum[g] = biasc[g * HH + d];

    const half8* Ald8 = (const half8*)Ald + lane;   // + jl*2048 + kc*64

    // publish half-index within a slot (pair of dims d, d^1 packed as u32),
    // in fp16 units; slot stride = 65536 fp16
    const unsigned int pidx = ((unsigned)grp * 2048 + ((unsigned)d >> 5) * 64 +
                               (((unsigned)d >> 3) & 3) * 16 + bl) * 8 + (d & 7);

    float c_reg = 0.f;
    __syncthreads();   // A-LDS ready

    for (int t = 0; t < TT_; ++t) {
        const int sIn  = (t - 1) & 63;
        const int sOut = t & 63;
        const int sPoi = (t + 8) & 63;

        // ---- issue xf loads FIRST (plain), then H (sc0sc1) ----
        const uint4v* Xsrc = (const uint4v*)Xpk + ((size_t)t * 32 + grp) * 64 + lane;
        uint4v xft[8];
#pragma unroll
        for (int k = 0; k < 8; ++k) {
            asm volatile("global_load_dwordx4 %0, %1, off"
                         : "=v"(xft[k]) : "v"(Xsrc + k * 256));
        }
        uint4v tmp[8];
        const uint4v* Hsrc = (const uint4v*)Hbuf + (size_t)sIn * 8192 +
                             (size_t)grp * 2048;
        if (t > 0) {
#pragma unroll
            for (int i = 0; i < 8; ++i) {
                asm volatile("global_load_dwordx4 %0, %1, off sc0 sc1"
                             : "=v"(tmp[i]) : "v"(Hsrc + i * 256 + tid));
            }
            // wait xf (oldest 8 + prev-iter stores); H stays in flight
            asm volatile("s_waitcnt vmcnt(8)" ::: "memory");
        } else {
            asm volatile("s_waitcnt vmcnt(0)" ::: "memory");
        }
        __builtin_amdgcn_sched_barrier(0);

        // ---- X-MFMAs (own tile) under the H shadow ----
        f32x4 accX = {0.f, 0.f, 0.f, 0.f};
#pragma unroll
        for (int k = 0; k < 8; ++k) {
            half8 bf = __builtin_bit_cast(half8, xft[k]);
            accX = __builtin_amdgcn_mfma_f32_16x16x32_f16(xa[k], bf, accX, 0, 0, 0);
        }

        // ---- H partials for all 4 tiles over this wave's 8 resident kc ----
        f32x4 accT[4];
#pragma unroll
        for (int jl = 0; jl < 4; ++jl) accT[jl] = (f32x4){0.f, 0.f, 0.f, 0.f};

        if (t > 0) {
            // poll: re-read ONLY still-poison vectors (good words are final)
            for (;;) {
                asm volatile("s_waitcnt vmcnt(0)" ::: "memory");
                __builtin_amdgcn_sched_barrier(0);
                int bad[8];
                int any = 0;
#pragma unroll
                for (int i = 0; i < 8; ++i) {
                    bad[i] = (tmp[i].x == 0xFFFFFFFFu) | (tmp[i].y == 0xFFFFFFFFu) |
                             (tmp[i].z == 0xFFFFFFFFu) | (tmp[i].w == 0xFFFFFFFFu);
                    any |= bad[i];
                }
                if (__all(any == 0)) break;
#pragma unroll
                for (int i = 0; i < 8; ++i) {
                    if (bad[i]) {
                        asm volatile("global_load_dwordx4 %0, %1, off sc0 sc1"
                                     : "=v"(tmp[i]) : "v"(Hsrc + i * 256 + tid));
                    }
                }
                __builtin_amdgcn_s_sleep(1);
            }

            // tmp[i] = B-frag(kc = i*4 + w); A-frags for all 4 tiles from LDS
#pragma unroll
            for (int i = 0; i < 8; ++i) {
                const int kc = i * 4 + w;
                half8 bf = __builtin_bit_cast(half8, tmp[i]);
#pragma unroll
                for (int jl = 0; jl < 4; ++jl) {
                    half8 a = Ald8[jl * 2048 + kc * 64];
                    accT[jl] = __builtin_amdgcn_mfma_f32_16x16x32_f16(a, bf, accT[jl], 0, 0, 0);
                }
            }
        }

        // ---- cross-wave K-reduction: pp[w][jl] = accT[jl]; owner jl sums ----
#pragma unroll
        for (int jl = 0; jl < 4; ++jl)
            pp[(w * 4 + jl) * 64 + lane] = accT[jl];
        __syncthreads();   // partials ready

        f32x4 s = accX;
#pragma unroll
        for (int w2 = 0; w2 < 4; ++w2)
            s += pp[(w2 * 4 + w) * 64 + lane];

        // ---- gates fully in-register ----
        float pi = s[0] + bsum[0];
        float pf = s[1] + bsum[1];
        float pg = s[2] + bsum[2];
        float po = s[3] + bsum[3];
        float ig = sigmoidf_(pi), fg = sigmoidf_(pf);
        float gg = tanhf_(pg),    og = sigmoidf_(po);
        c_reg = fg * c_reg + ig * gg;
        float h = og * tanhf_(c_reg);

        // ---- publish h(t) EVERY step (slot 63 at t=511 feeds hdec_mfma) ----
        float hp = __shfl_xor(h, 16);    // partner q^1 -> dim d^1
        if (!(q & 1)) {
            _Float16 h0 = (_Float16)h, h1 = (_Float16)hp;
            unsigned int pk = (unsigned int)__builtin_bit_cast(unsigned short, h0) |
                              ((unsigned int)__builtin_bit_cast(unsigned short, h1) << 16);
            unsigned int* po_ = (unsigned int*)(Hbuf + (size_t)sOut * 65536 + pidx);
            asm volatile("global_store_dword %0, %1, off sc0 sc1"
                         :: "v"(po_), "v"(pk) : "memory");
            unsigned int* pz = (unsigned int*)(Hbuf + (size_t)sPoi * 65536 + pidx);
            unsigned int poison = 0xFFFFFFFFu;
            asm volatile("global_store_dword %0, %1, off sc0 sc1"
                         :: "v"(pz), "v"(poison) : "memory");
        }
        // stores drained by next step's poll vmcnt; no flags, no drains here

        if (t < TT_ - 1) __syncthreads();   // protect pp before next exchange
    }

    // ---- final state for decoder ----
    cT[d * 64 + b] = c_reg;
    // final h is in Hbuf slot (TT_-1)&63 in B-frag layout (read by hdec_mfma)
}

// ---------------- hdec_mfma: hdecg = h_final @ dec_Whh^T + biases ----------------
// grid 64, block 256 (4 waves). Wave jt = bid*4+w: D[16 rows = 4dim x 4gate]
// x 16 b per group g; B-frags straight from Hbuf slot (TT_-1)&63.
__global__ __launch_bounds__(256)
void hdec_mfma(const _Float16* __restrict__ Ahhpk,
               const _Float16* __restrict__ Hfin,
               const float* __restrict__ biascd,
               float* __restrict__ hdecg)
{
    const int tid = threadIdx.x;
    const int lane = tid & 63, w = tid >> 6;
    const int jt = blockIdx.x * 4 + w;
    const int q = lane >> 4, bl = lane & 15;

    const half8* A8 = (const half8*)Ahhpk + ((size_t)jt * 32) * 64 + lane;
    const half8* H8 = (const half8*)Hfin + lane;

    f32x4 acc[4];
#pragma unroll
    for (int g = 0; g < 4; ++g) acc[g] = (f32x4){0.f, 0.f, 0.f, 0.f};
#pragma unroll 4
    for (int kc = 0; kc < 32; ++kc) {
        half8 a = A8[kc * 64];
#pragma unroll
        for (int g = 0; g < 4; ++g) {
            half8 bf = H8[g * 2048 + kc * 64];
            acc[g] = __builtin_amdgcn_mfma_f32_16x16x32_f16(a, bf, acc[g], 0, 0, 0);
        }
    }
    int d = jt * 4 + q;
#pragma unroll
    for (int g = 0; g < 4; ++g)
#pragma unroll
        for (int r = 0; r < 4; ++r)
            hdecg[((size_t)r * HH + d) * 64 + g * 16 + bl] = acc[g][r] + biascd[r * HH + d];
}

// ---------------- MFMA decoder (unchanged) ----------------
__global__ __launch_bounds__(256)
void dec_mfma(const _Float16* __restrict__ Adecpk,
              const _Float16* __restrict__ fcWpk,
              const _Float16* __restrict__ Xpk,
              const float* __restrict__ hdecg,
              const float* __restrict__ cT,
              const float* __restrict__ fcb,
              float* __restrict__ out)
{
    __shared__ __align__(16) _Float16 Hn[32 * 64 * 8];   // 32 KB
    __shared__ __align__(16) float outl[16][260];
    const int tid = threadIdx.x;
    const int lane = tid & 63, w = tid >> 6;
    const int t = blockIdx.x >> 2, bq4 = blockIdx.x & 3;
    const int q = lane >> 4, bl = lane & 15;
    const int bg = bq4 * 16 + bl;

    const half8* X8 = (const half8*)Xpk + ((size_t)t * 32 + bq4) * 64 + lane;
    half8 xf[8];
#pragma unroll
    for (int kc2 = 0; kc2 < 8; ++kc2) xf[kc2] = X8[kc2 * 256];

    const half8* AD = (const half8*)Adecpk + lane;
    for (int dqi = 0; dqi < 32; ++dqi) {
        int dq = w * 32 + dqi;
#pragma unroll
        for (int t2 = 0; t2 < 2; ++t2) {
            f32x4 acc = {0.f, 0.f, 0.f, 0.f};
#pragma unroll
            for (int kc2 = 0; kc2 < 8; ++kc2) {
                half8 a = AD[((size_t)(dq * 2 + t2) * 8 + kc2) * 64];
                acc = __builtin_amdgcn_mfma_f32_16x16x32_f16(a, xf[kc2], acc, 0, 0, 0);
            }
            int d = dq * 8 + t2 * 4 + q;
            float cv = cT[d * 64 + bg];
            float pi = acc[0] + hdecg[(size_t)(0 * HH + d) * 64 + bg];
            float pf = acc[1] + hdecg[(size_t)(1 * HH + d) * 64 + bg];
            float pg = acc[2] + hdecg[(size_t)(2 * HH + d) * 64 + bg];
            float po = acc[3] + hdecg[(size_t)(3 * HH + d) * 64 + bg];
            float ig = sigmoidf_(pi), fg = sigmoidf_(pf);
            float gg = tanhf_(pg),    og = sigmoidf_(po);
            float cn = fg * cv + ig * gg;
            float h = og * tanhf_(cn);
            Hn[((d >> 5) * 64 + ((d >> 3) & 3) * 16 + bl) * 8 + (d & 7)] = (_Float16)h;
        }
    }
    __syncthreads();

    const half8* Hn8 = (const half8*)Hn + lane;
    const half8* FW = (const half8*)fcWpk + lane;
#pragma unroll
    for (int oti = 0; oti < 4; ++oti) {
        int ot = w * 4 + oti;
        f32x4 acc = {0.f, 0.f, 0.f, 0.f};
        for (int kc = 0; kc < 32; ++kc) {
            half8 a  = FW[((size_t)ot * 32 + kc) * 64];
            half8 bf = Hn8[kc * 64];
            acc = __builtin_amdgcn_mfma_f32_16x16x32_f16(a, bf, acc, 0, 0, 0);
        }
#pragma unroll
        for (int r = 0; r < 4; ++r) {
            int o = ot * 16 + q * 4 + r;
            outl[bl][o] = acc[r] + fcb[o];
        }
    }
    __syncthreads();

#pragma unroll
    for (int i = 0; i < 16; ++i) {
        int b = bq4 * 16 + i;
        out[((size_t)b * TT_ + t) * OO + tid] = outl[i][tid];
    }
}

extern "C" void kernel_launch(void* const* d_in, const int* in_sizes, int n_in,
                              void* d_out, int out_size, void* d_ws, size_t ws_size,
                              hipStream_t stream) {
    const float* x    = (const float*)d_in[0];
    const float* eWih = (const float*)d_in[1];
    const float* eWhh = (const float*)d_in[2];
    const float* ebih = (const float*)d_in[3];
    const float* ebhh = (const float*)d_in[4];
    const float* dWih = (const float*)d_in[5];
    const float* dWhh = (const float*)d_in[6];
    const float* dbih = (const float*)d_in[7];
    const float* dbhh = (const float*)d_in[8];
    const float* fcW  = (const float*)d_in[9];
    const float* fcb  = (const float*)d_in[10];

    // ws layout (f32 words): cT 65536 | hdecg 262144 | biasc 4096 | biascd 4096 |
    // then fp16: Hbuf 64x65536 = 4194304 | Apk 5242880 | Xpk 8388608 |
    // Adecpk 1048576 | fcWpk 262144 | Ahhpk 4194304  (~48 MB total)
    float* ws     = (float*)d_ws;
    float* cT     = ws;
    float* hdecg  = ws + 65536;
    float* biasc  = ws + 327680;
    float* biascd = ws + 331776;
    _Float16* fp  = (_Float16*)(ws + 335872);
    _Float16* Hbuf = fp;
    _Float16* Apk  = fp + 4194304;
    _Float16* Xpk  = Apk + 5242880;
    _Float16* Adecpk = Xpk + 8388608;
    _Float16* fcWpk  = Adecpk + 1048576;
    _Float16* Ahhpk  = fcWpk + 262144;

    pack_a2<<<dim3(2560), dim3(256), 0, stream>>>(eWhh, eWih, Apk);
    pack_x<<<dim3(4096), dim3(256), 0, stream>>>(x, Xpk);
    pack_bias<<<dim3(16), dim3(256), 0, stream>>>(ebih, ebhh, biasc);
    pack_bias<<<dim3(16), dim3(256), 0, stream>>>(dbih, dbhh, biascd);
    pack_adec<<<dim3(512), dim3(256), 0, stream>>>(dWih, Adecpk);
    pack_fcw<<<dim3(128), dim3(256), 0, stream>>>(fcW, fcWpk);
    pack_ahh<<<dim3(2048), dim3(256), 0, stream>>>(dWhh, Ahhpk);
    // poison all 64 h slots (0xFF bytes -> u32 0xFFFFFFFF = fp16 NaN pair)
    hipMemsetAsync(Hbuf, 0xFF, (size_t)4194304 * sizeof(_Float16), stream);

    enc_persist<<<dim3(256), dim3(256), 0, stream>>>(
        Apk, Xpk, Hbuf, biasc, cT);

    const _Float16* Hfin = Hbuf + (size_t)((TT_ - 1) & 63) * 65536;
    hdec_mfma<<<dim3(64), dim3(256), 0, stream>>>(Ahhpk, Hfin, biascd, hdecg);
    dec_mfma<<<dim3(2048), dim3(256), 0, stream>>>(Adecpk, fcWpk, Xpk, hdecg, cT,
                                                   fcb, (float*)d_out);
}